// Round 1
// baseline (1204.995 us; speedup 1.0000x reference)
//
#include <hip/hip_runtime.h>

#define N_NODES 50000
#define N_EDGES 800000
#define N_GRAPHS 64
#define D 90
#define S 96   // padded feature stride (floats)

// ---------------- CSR build ----------------
__global__ void k_count(const int* __restrict__ dst, int* __restrict__ cnt) {
    int e = blockIdx.x * 256 + threadIdx.x;
    if (e < N_EDGES) atomicAdd(&cnt[dst[e]], 1);
}

__global__ void k_scan1(const int* __restrict__ cnt, int* __restrict__ bsum) {
    __shared__ int s[256];
    int t = threadIdx.x;
    int i = blockIdx.x * 256 + t;
    s[t] = (i < N_NODES) ? cnt[i] : 0;
    __syncthreads();
    for (int o = 128; o > 0; o >>= 1) { if (t < o) s[t] += s[t + o]; __syncthreads(); }
    if (t == 0) bsum[blockIdx.x] = s[0];
}

__global__ void k_scan2(const int* __restrict__ bsum, int* __restrict__ bpre, int nb) {
    __shared__ int s[256];
    int t = threadIdx.x;
    int v = (t < nb) ? bsum[t] : 0;
    s[t] = v; __syncthreads();
    for (int o = 1; o < 256; o <<= 1) {
        int x = (t >= o) ? s[t - o] : 0;
        __syncthreads();
        s[t] += x;
        __syncthreads();
    }
    bpre[t] = s[t] - v;  // exclusive
}

__global__ void k_scan3(const int* __restrict__ cnt, const int* __restrict__ bpre,
                        int* __restrict__ off, int* __restrict__ cursor) {
    __shared__ int s[256];
    int t = threadIdx.x;
    int i = blockIdx.x * 256 + t;
    int v = (i < N_NODES) ? cnt[i] : 0;
    s[t] = v; __syncthreads();
    for (int o = 1; o < 256; o <<= 1) {
        int x = (t >= o) ? s[t - o] : 0;
        __syncthreads();
        s[t] += x;
        __syncthreads();
    }
    int excl = s[t] - v + bpre[blockIdx.x];
    if (i < N_NODES) { off[i] = excl; cursor[i] = excl; }
    if (i == N_NODES - 1) off[N_NODES] = excl + v;
}

__global__ void k_fill(const int* __restrict__ src, const int* __restrict__ dst,
                       int* __restrict__ cursor, int* __restrict__ csr) {
    int e = blockIdx.x * 256 + threadIdx.x;
    if (e >= N_EDGES) return;
    int p = atomicAdd(&cursor[dst[e]], 1);
    csr[p] = src[e];
}

// ---------------- W pad/pack: [layer][{l,r}][96][96], zero-padded ----------------
__global__ void k_prepw(const float* __restrict__ w1l, const float* __restrict__ w1r,
                        const float* __restrict__ w2l, const float* __restrict__ w2r,
                        const float* __restrict__ w3l, const float* __restrict__ w3r,
                        float* __restrict__ Wpad) {
    int idx = blockIdx.x * 256 + threadIdx.x;
    const int per = 96 * 96;
    if (idx >= 6 * per) return;
    int slot = idx / per, rem = idx - slot * per;
    int j = rem / 96, k = rem - j * 96;
    const float* src;
    switch (slot) {
        case 0: src = w1l; break;
        case 1: src = w1r; break;
        case 2: src = w2l; break;
        case 3: src = w2r; break;
        case 4: src = w3l; break;
        default: src = w3r; break;
    }
    Wpad[idx] = (j < D && k < D) ? src[j * D + k] : 0.f;
}

// ---------------- mean aggregation: 1 wave per node ----------------
__global__ void k_agg(const float* __restrict__ hin, int hs,
                      const int* __restrict__ off, const int* __restrict__ csr,
                      float* __restrict__ outp) {
    int wid  = (blockIdx.x * 256 + threadIdx.x) >> 6;
    int lane = threadIdx.x & 63;
    if (wid >= N_NODES) return;
    int beg = off[wid], end = off[wid + 1];
    float a0 = 0.f, a1 = 0.f;
    for (int e = beg; e < end; ++e) {
        int sIdx = csr[e];
        const float* row = hin + sIdx * hs;
        a0 += row[lane];
        if (lane < D - 64) a1 += row[64 + lane];
    }
    float inv = 1.0f / fmaxf((float)(end - beg), 1.0f);
    outp[wid * S + lane] = a0 * inv;
    if (lane < 32) outp[wid * S + 64 + lane] = (lane < D - 64) ? a1 * inv : 0.f;
}

// ---------------- fused dual-GEMM + bias + ReLU ----------------
// out[n][j] = relu(bias[j] + sum_k agg[n][k]*Wl[j][k] + h[n][k]*Wr[j][k])
// block: 64 nodes; thread: 4 nodes x 6 cols
__global__ __launch_bounds__(256) void k_gemm(
    const float* __restrict__ Apart,  // [N][S], pads zeroed
    const float* __restrict__ Hin,    // [N][hs]
    int hs,
    const float* __restrict__ Wpad,   // [2][96][96] (l then r)
    const float* __restrict__ bias,   // [D]
    float* __restrict__ outp)         // [N][S] (may alias Apart)
{
    __shared__ __align__(16) float aT[64][100];
    __shared__ __align__(16) float hT[64][100];
    int tid = threadIdx.x;
    int nb = blockIdx.x * 64;
    for (int idx = tid; idx < 64 * S; idx += 256) {
        int r = idx / S, k = idx - r * S;
        int n = nb + r;
        float av = 0.f, hv = 0.f;
        if (n < N_NODES) {
            av = Apart[n * S + k];
            if (k < D) hv = Hin[n * hs + k];
        }
        aT[r][k] = av;
        hT[r][k] = hv;
    }
    __syncthreads();

    int w = tid >> 6, lane = tid & 63;
    int cg = lane & 15, ng = lane >> 4;
    int r0 = w * 16 + ng * 4;
    int j0 = cg * 6;

    float acc[4][6];
    #pragma unroll
    for (int jj = 0; jj < 6; ++jj) {
        float b = (j0 + jj < D) ? bias[j0 + jj] : 0.f;
        #pragma unroll
        for (int i = 0; i < 4; ++i) acc[i][jj] = b;
    }

    const float4* wl4 = (const float4*)(Wpad);
    const float4* wr4 = (const float4*)(Wpad + 96 * 96);
    #pragma unroll 2
    for (int kc = 0; kc < 24; ++kc) {
        float4 a4[4], h4[4];
        #pragma unroll
        for (int i = 0; i < 4; ++i) {
            a4[i] = *(const float4*)&aT[r0 + i][kc * 4];
            h4[i] = *(const float4*)&hT[r0 + i][kc * 4];
        }
        #pragma unroll
        for (int jj = 0; jj < 6; ++jj) {
            float4 wlv = wl4[(j0 + jj) * 24 + kc];
            float4 wrv = wr4[(j0 + jj) * 24 + kc];
            #pragma unroll
            for (int i = 0; i < 4; ++i) {
                acc[i][jj] += a4[i].x * wlv.x + a4[i].y * wlv.y
                            + a4[i].z * wlv.z + a4[i].w * wlv.w
                            + h4[i].x * wrv.x + h4[i].y * wrv.y
                            + h4[i].z * wrv.z + h4[i].w * wrv.w;
            }
        }
    }

    #pragma unroll
    for (int i = 0; i < 4; ++i) {
        int n = nb + r0 + i;
        if (n >= N_NODES) continue;
        #pragma unroll
        for (int jj = 0; jj < 6; ++jj) {
            int j = j0 + jj;
            if (j < D) outp[n * S + j] = fmaxf(acc[i][jj], 0.f);
        }
    }
}

// ---------------- graph mean pool (atomics) ----------------
__global__ void k_pool(const float* __restrict__ h, const int* __restrict__ batch,
                       float* __restrict__ pooled, float* __restrict__ cntg) {
    int wid  = (blockIdx.x * 256 + threadIdx.x) >> 6;
    int lane = threadIdx.x & 63;
    if (wid >= N_NODES) return;
    int g = batch[wid];
    atomicAdd(&pooled[g * D + lane], h[wid * S + lane]);
    if (lane < D - 64) atomicAdd(&pooled[g * D + 64 + lane], h[wid * S + 64 + lane]);
    if (lane == 0) atomicAdd(&cntg[g], 1.0f);
}

// ---------------- final MLP (single block) ----------------
__global__ void k_mlp(const float* __restrict__ pooled, const float* __restrict__ cntg,
                      const float* __restrict__ Wf1, const float* __restrict__ bf1,
                      const float* __restrict__ Wf2, const float* __restrict__ bf2,
                      float* __restrict__ outp) {
    __shared__ float P[N_GRAPHS][92];
    __shared__ float H4[N_GRAPHS][32];
    int tid = threadIdx.x;
    for (int idx = tid; idx < N_GRAPHS * D; idx += 256) {
        int g = idx / D, d = idx - g * D;
        P[g][d] = pooled[idx] / fmaxf(cntg[g], 1.0f);
    }
    __syncthreads();
    for (int idx = tid; idx < N_GRAPHS * 32; idx += 256) {
        int g = idx >> 5, c = idx & 31;
        float acc = bf1[c];
        for (int d = 0; d < D; ++d) acc += P[g][d] * Wf1[c * D + d];
        H4[g][c] = fmaxf(acc, 0.f);
    }
    __syncthreads();
    if (tid < N_GRAPHS) {
        float acc = bf2[0];
        #pragma unroll
        for (int c = 0; c < 32; ++c) acc += H4[tid][c] * Wf2[c];
        outp[tid] = acc;
    }
}

extern "C" void kernel_launch(void* const* d_in, const int* in_sizes, int n_in,
                              void* d_out, int out_size, void* d_ws, size_t ws_size,
                              hipStream_t stream) {
    const float* x    = (const float*)d_in[0];
    const int*   ei   = (const int*)d_in[1];
    const int*   batch= (const int*)d_in[2];
    const float* W1l  = (const float*)d_in[3];
    const float* b1   = (const float*)d_in[4];
    const float* W1r  = (const float*)d_in[5];
    const float* W2l  = (const float*)d_in[6];
    const float* b2   = (const float*)d_in[7];
    const float* W2r  = (const float*)d_in[8];
    const float* W3l  = (const float*)d_in[9];
    const float* b3   = (const float*)d_in[10];
    const float* W3r  = (const float*)d_in[11];
    const float* Wf1  = (const float*)d_in[12];
    const float* bf1  = (const float*)d_in[13];
    const float* Wf2  = (const float*)d_in[14];
    const float* bf2  = (const float*)d_in[15];
    const int* srcI = ei;
    const int* dstI = ei + N_EDGES;

    char* base = (char*)d_ws;
    size_t o = 0;
    auto alloc = [&](size_t bytes) -> void* {
        void* p = base + o;
        o = (o + bytes + 255) & ~(size_t)255;
        return p;
    };
    int*   cnt    = (int*)alloc((size_t)N_NODES * 4);
    int*   cursor = (int*)alloc((size_t)N_NODES * 4);
    int*   off    = (int*)alloc((size_t)(N_NODES + 1) * 4);
    int*   bsum   = (int*)alloc(256 * 4);
    int*   bpre   = (int*)alloc(256 * 4);
    int*   csr    = (int*)alloc((size_t)N_EDGES * 4);
    float* bufA   = (float*)alloc((size_t)N_NODES * S * 4);
    float* bufB   = (float*)alloc((size_t)N_NODES * S * 4);
    float* Wpad   = (float*)alloc((size_t)6 * 96 * 96 * 4);
    float* pooled = (float*)alloc((size_t)(N_GRAPHS * D + N_GRAPHS) * 4);
    float* cntg   = pooled + N_GRAPHS * D;

    hipMemsetAsync(cnt, 0, (size_t)N_NODES * 4, stream);
    hipMemsetAsync(pooled, 0, (size_t)(N_GRAPHS * D + N_GRAPHS) * 4, stream);

    const int NB = (N_NODES + 255) / 256;  // 196
    k_count<<<(N_EDGES + 255) / 256, 256, 0, stream>>>(dstI, cnt);
    k_scan1<<<NB, 256, 0, stream>>>(cnt, bsum);
    k_scan2<<<1, 256, 0, stream>>>(bsum, bpre, NB);
    k_scan3<<<NB, 256, 0, stream>>>(cnt, bpre, off, cursor);
    k_fill<<<(N_EDGES + 255) / 256, 256, 0, stream>>>(srcI, dstI, cursor, csr);
    k_prepw<<<(6 * 96 * 96 + 255) / 256, 256, 0, stream>>>(W1l, W1r, W2l, W2r, W3l, W3r, Wpad);

    const int AGG_BLOCKS  = N_NODES / 4;         // 12500 (4 waves/block, 1 node/wave)
    const int GEMM_BLOCKS = (N_NODES + 63) / 64; // 782

    // layer 1
    k_agg<<<AGG_BLOCKS, 256, 0, stream>>>(x, D, off, csr, bufA);
    k_gemm<<<GEMM_BLOCKS, 256, 0, stream>>>(bufA, x, D, Wpad, b1, bufA);
    // layer 2
    k_agg<<<AGG_BLOCKS, 256, 0, stream>>>(bufA, S, off, csr, bufB);
    k_gemm<<<GEMM_BLOCKS, 256, 0, stream>>>(bufB, bufA, S, Wpad + 2 * 96 * 96, b2, bufB);
    // layer 3
    k_agg<<<AGG_BLOCKS, 256, 0, stream>>>(bufB, S, off, csr, bufA);
    k_gemm<<<GEMM_BLOCKS, 256, 0, stream>>>(bufA, bufB, S, Wpad + 4 * 96 * 96, b3, bufA);

    k_pool<<<AGG_BLOCKS, 256, 0, stream>>>(bufA, batch, pooled, cntg);
    k_mlp<<<1, 256, 0, stream>>>(pooled, cntg, Wf1, bf1, Wf2, bf2, (float*)d_out);
}

// Round 2
// 850.926 us; speedup vs baseline: 1.4161x; 1.4161x over previous
//
#include <hip/hip_runtime.h>

#define N_NODES 50000
#define N_EDGES 800000
#define N_GRAPHS 64
#define D 90
#define S 96   // padded feature stride (floats)

// ---------------- CSR build ----------------
__global__ void k_count(const int* __restrict__ dst, int* __restrict__ cnt) {
    int e = blockIdx.x * 256 + threadIdx.x;
    if (e < N_EDGES) atomicAdd(&cnt[dst[e]], 1);
}

__global__ void k_scan1(const int* __restrict__ cnt, int* __restrict__ bsum) {
    __shared__ int s[256];
    int t = threadIdx.x;
    int i = blockIdx.x * 256 + t;
    s[t] = (i < N_NODES) ? cnt[i] : 0;
    __syncthreads();
    for (int o = 128; o > 0; o >>= 1) { if (t < o) s[t] += s[t + o]; __syncthreads(); }
    if (t == 0) bsum[blockIdx.x] = s[0];
}

__global__ void k_scan2(const int* __restrict__ bsum, int* __restrict__ bpre, int nb) {
    __shared__ int s[256];
    int t = threadIdx.x;
    int v = (t < nb) ? bsum[t] : 0;
    s[t] = v; __syncthreads();
    for (int o = 1; o < 256; o <<= 1) {
        int x = (t >= o) ? s[t - o] : 0;
        __syncthreads();
        s[t] += x;
        __syncthreads();
    }
    bpre[t] = s[t] - v;  // exclusive
}

__global__ void k_scan3(const int* __restrict__ cnt, const int* __restrict__ bpre,
                        int* __restrict__ off, int* __restrict__ cursor) {
    __shared__ int s[256];
    int t = threadIdx.x;
    int i = blockIdx.x * 256 + t;
    int v = (i < N_NODES) ? cnt[i] : 0;
    s[t] = v; __syncthreads();
    for (int o = 1; o < 256; o <<= 1) {
        int x = (t >= o) ? s[t - o] : 0;
        __syncthreads();
        s[t] += x;
        __syncthreads();
    }
    int excl = s[t] - v + bpre[blockIdx.x];
    if (i < N_NODES) { off[i] = excl; cursor[i] = excl; }
    if (i == N_NODES - 1) off[N_NODES] = excl + v;
}

__global__ void k_fill(const int* __restrict__ src, const int* __restrict__ dst,
                       int* __restrict__ cursor, int* __restrict__ csr) {
    int e = blockIdx.x * 256 + threadIdx.x;
    if (e >= N_EDGES) return;
    int p = atomicAdd(&cursor[dst[e]], 1);
    csr[p] = src[e];
}

// ---------------- W pad/pack: [layer][{l,r}][96][96], zero-padded ----------------
__global__ void k_prepw(const float* __restrict__ w1l, const float* __restrict__ w1r,
                        const float* __restrict__ w2l, const float* __restrict__ w2r,
                        const float* __restrict__ w3l, const float* __restrict__ w3r,
                        float* __restrict__ Wpad) {
    int idx = blockIdx.x * 256 + threadIdx.x;
    const int per = 96 * 96;
    if (idx >= 6 * per) return;
    int slot = idx / per, rem = idx - slot * per;
    int j = rem / 96, k = rem - j * 96;
    const float* src;
    switch (slot) {
        case 0: src = w1l; break;
        case 1: src = w1r; break;
        case 2: src = w2l; break;
        case 3: src = w2r; break;
        case 4: src = w3l; break;
        default: src = w3r; break;
    }
    Wpad[idx] = (j < D && k < D) ? src[j * D + k] : 0.f;
}

// ---------------- mean aggregation: 1 wave per node ----------------
__global__ void k_agg(const float* __restrict__ hin, int hs,
                      const int* __restrict__ off, const int* __restrict__ csr,
                      float* __restrict__ outp) {
    int wid  = (blockIdx.x * 256 + threadIdx.x) >> 6;
    int lane = threadIdx.x & 63;
    if (wid >= N_NODES) return;
    int beg = off[wid], end = off[wid + 1];
    float a0 = 0.f, a1 = 0.f;
    for (int e = beg; e < end; ++e) {
        int sIdx = csr[e];
        const float* row = hin + sIdx * hs;
        a0 += row[lane];
        if (lane < D - 64) a1 += row[64 + lane];
    }
    float inv = 1.0f / fmaxf((float)(end - beg), 1.0f);
    outp[wid * S + lane] = a0 * inv;
    if (lane < 32) outp[wid * S + 64 + lane] = (lane < D - 64) ? a1 * inv : 0.f;
}

// ---------------- fused dual-GEMM + bias + ReLU ----------------
// out[n][j] = relu(bias[j] + sum_k agg[n][k]*Wl[j][k] + h[n][k]*Wr[j][k])
// block: 64 nodes; thread: 4 nodes x 6 cols
__global__ __launch_bounds__(256) void k_gemm(
    const float* __restrict__ Apart,  // [N][S], pads zeroed
    const float* __restrict__ Hin,    // [N][hs]
    int hs,
    const float* __restrict__ Wpad,   // [2][96][96] (l then r)
    const float* __restrict__ bias,   // [D]
    float* __restrict__ outp)         // [N][S] (may alias Apart)
{
    __shared__ __align__(16) float aT[64][100];
    __shared__ __align__(16) float hT[64][100];
    int tid = threadIdx.x;
    int nb = blockIdx.x * 64;
    for (int idx = tid; idx < 64 * S; idx += 256) {
        int r = idx / S, k = idx - r * S;
        int n = nb + r;
        float av = 0.f, hv = 0.f;
        if (n < N_NODES) {
            av = Apart[n * S + k];
            if (k < D) hv = Hin[n * hs + k];
        }
        aT[r][k] = av;
        hT[r][k] = hv;
    }
    __syncthreads();

    int w = tid >> 6, lane = tid & 63;
    int cg = lane & 15, ng = lane >> 4;
    int r0 = w * 16 + ng * 4;
    int j0 = cg * 6;

    float acc[4][6];
    #pragma unroll
    for (int jj = 0; jj < 6; ++jj) {
        float b = (j0 + jj < D) ? bias[j0 + jj] : 0.f;
        #pragma unroll
        for (int i = 0; i < 4; ++i) acc[i][jj] = b;
    }

    const float4* wl4 = (const float4*)(Wpad);
    const float4* wr4 = (const float4*)(Wpad + 96 * 96);
    #pragma unroll 2
    for (int kc = 0; kc < 24; ++kc) {
        float4 a4[4], h4[4];
        #pragma unroll
        for (int i = 0; i < 4; ++i) {
            a4[i] = *(const float4*)&aT[r0 + i][kc * 4];
            h4[i] = *(const float4*)&hT[r0 + i][kc * 4];
        }
        #pragma unroll
        for (int jj = 0; jj < 6; ++jj) {
            float4 wlv = wl4[(j0 + jj) * 24 + kc];
            float4 wrv = wr4[(j0 + jj) * 24 + kc];
            #pragma unroll
            for (int i = 0; i < 4; ++i) {
                acc[i][jj] += a4[i].x * wlv.x + a4[i].y * wlv.y
                            + a4[i].z * wlv.z + a4[i].w * wlv.w
                            + h4[i].x * wrv.x + h4[i].y * wrv.y
                            + h4[i].z * wrv.z + h4[i].w * wrv.w;
            }
        }
    }

    #pragma unroll
    for (int i = 0; i < 4; ++i) {
        int n = nb + r0 + i;
        if (n >= N_NODES) continue;
        #pragma unroll
        for (int jj = 0; jj < 6; ++jj) {
            int j = j0 + jj;
            if (j < D) outp[n * S + j] = fmaxf(acc[i][jj], 0.f);
        }
    }
}

// ---------------- graph mean pool: segmented reduction (batch is sorted) ----------------
// Each wave owns a contiguous node range; flush per-graph partial sums on id change.
#define POOL_WAVES 512
__global__ void k_pool(const float* __restrict__ h, const int* __restrict__ batch,
                       float* __restrict__ pooled, float* __restrict__ cntg) {
    int wid  = (blockIdx.x * blockDim.x + threadIdx.x) >> 6;
    int lane = threadIdx.x & 63;
    const int per = (N_NODES + POOL_WAVES - 1) / POOL_WAVES;
    int beg = wid * per;
    int end = beg + per; if (end > N_NODES) end = N_NODES;
    if (beg >= end) return;
    int cur = batch[beg];
    float a0 = 0.f, a1 = 0.f, c = 0.f;
    for (int n = beg; n < end; ++n) {
        int g = batch[n];
        if (g != cur) {
            atomicAdd(&pooled[cur * D + lane], a0);
            if (lane < D - 64) atomicAdd(&pooled[cur * D + 64 + lane], a1);
            if (lane == 0) atomicAdd(&cntg[cur], c);
            a0 = a1 = c = 0.f;
            cur = g;
        }
        a0 += h[n * S + lane];
        if (lane < D - 64) a1 += h[n * S + 64 + lane];
        c += 1.f;
    }
    atomicAdd(&pooled[cur * D + lane], a0);
    if (lane < D - 64) atomicAdd(&pooled[cur * D + 64 + lane], a1);
    if (lane == 0) atomicAdd(&cntg[cur], c);
}

// ---------------- final MLP (single block) ----------------
__global__ void k_mlp(const float* __restrict__ pooled, const float* __restrict__ cntg,
                      const float* __restrict__ Wf1, const float* __restrict__ bf1,
                      const float* __restrict__ Wf2, const float* __restrict__ bf2,
                      float* __restrict__ outp) {
    __shared__ float P[N_GRAPHS][92];
    __shared__ float H4[N_GRAPHS][32];
    int tid = threadIdx.x;
    for (int idx = tid; idx < N_GRAPHS * D; idx += 256) {
        int g = idx / D, d = idx - g * D;
        P[g][d] = pooled[idx] / fmaxf(cntg[g], 1.0f);
    }
    __syncthreads();
    for (int idx = tid; idx < N_GRAPHS * 32; idx += 256) {
        int g = idx >> 5, c = idx & 31;
        float acc = bf1[c];
        for (int d = 0; d < D; ++d) acc += P[g][d] * Wf1[c * D + d];
        H4[g][c] = fmaxf(acc, 0.f);
    }
    __syncthreads();
    if (tid < N_GRAPHS) {
        float acc = bf2[0];
        #pragma unroll
        for (int c = 0; c < 32; ++c) acc += H4[tid][c] * Wf2[c];
        outp[tid] = acc;
    }
}

extern "C" void kernel_launch(void* const* d_in, const int* in_sizes, int n_in,
                              void* d_out, int out_size, void* d_ws, size_t ws_size,
                              hipStream_t stream) {
    const float* x    = (const float*)d_in[0];
    const int*   ei   = (const int*)d_in[1];
    const int*   batch= (const int*)d_in[2];
    const float* W1l  = (const float*)d_in[3];
    const float* b1   = (const float*)d_in[4];
    const float* W1r  = (const float*)d_in[5];
    const float* W2l  = (const float*)d_in[6];
    const float* b2   = (const float*)d_in[7];
    const float* W2r  = (const float*)d_in[8];
    const float* W3l  = (const float*)d_in[9];
    const float* b3   = (const float*)d_in[10];
    const float* W3r  = (const float*)d_in[11];
    const float* Wf1  = (const float*)d_in[12];
    const float* bf1  = (const float*)d_in[13];
    const float* Wf2  = (const float*)d_in[14];
    const float* bf2  = (const float*)d_in[15];
    const int* srcI = ei;
    const int* dstI = ei + N_EDGES;

    char* base = (char*)d_ws;
    size_t o = 0;
    auto alloc = [&](size_t bytes) -> void* {
        void* p = base + o;
        o = (o + bytes + 255) & ~(size_t)255;
        return p;
    };
    int*   cnt    = (int*)alloc((size_t)N_NODES * 4);
    int*   cursor = (int*)alloc((size_t)N_NODES * 4);
    int*   off    = (int*)alloc((size_t)(N_NODES + 1) * 4);
    int*   bsum   = (int*)alloc(256 * 4);
    int*   bpre   = (int*)alloc(256 * 4);
    int*   csr    = (int*)alloc((size_t)N_EDGES * 4);
    float* bufA   = (float*)alloc((size_t)N_NODES * S * 4);
    float* bufB   = (float*)alloc((size_t)N_NODES * S * 4);
    float* Wpad   = (float*)alloc((size_t)6 * 96 * 96 * 4);
    float* pooled = (float*)alloc((size_t)(N_GRAPHS * D + N_GRAPHS) * 4);
    float* cntg   = pooled + N_GRAPHS * D;

    hipMemsetAsync(cnt, 0, (size_t)N_NODES * 4, stream);
    hipMemsetAsync(pooled, 0, (size_t)(N_GRAPHS * D + N_GRAPHS) * 4, stream);

    const int NB = (N_NODES + 255) / 256;  // 196
    k_count<<<(N_EDGES + 255) / 256, 256, 0, stream>>>(dstI, cnt);
    k_scan1<<<NB, 256, 0, stream>>>(cnt, bsum);
    k_scan2<<<1, 256, 0, stream>>>(bsum, bpre, NB);
    k_scan3<<<NB, 256, 0, stream>>>(cnt, bpre, off, cursor);
    k_fill<<<(N_EDGES + 255) / 256, 256, 0, stream>>>(srcI, dstI, cursor, csr);
    k_prepw<<<(6 * 96 * 96 + 255) / 256, 256, 0, stream>>>(W1l, W1r, W2l, W2r, W3l, W3r, Wpad);

    const int AGG_BLOCKS  = N_NODES / 4;         // 12500 (4 waves/block, 1 node/wave)
    const int GEMM_BLOCKS = (N_NODES + 63) / 64; // 782

    // layer 1
    k_agg<<<AGG_BLOCKS, 256, 0, stream>>>(x, D, off, csr, bufA);
    k_gemm<<<GEMM_BLOCKS, 256, 0, stream>>>(bufA, x, D, Wpad, b1, bufA);
    // layer 2
    k_agg<<<AGG_BLOCKS, 256, 0, stream>>>(bufA, S, off, csr, bufB);
    k_gemm<<<GEMM_BLOCKS, 256, 0, stream>>>(bufB, bufA, S, Wpad + 2 * 96 * 96, b2, bufB);
    // layer 3
    k_agg<<<AGG_BLOCKS, 256, 0, stream>>>(bufB, S, off, csr, bufA);
    k_gemm<<<GEMM_BLOCKS, 256, 0, stream>>>(bufA, bufB, S, Wpad + 4 * 96 * 96, b3, bufA);

    k_pool<<<POOL_WAVES / 4, 256, 0, stream>>>(bufA, batch, pooled, cntg);
    k_mlp<<<1, 256, 0, stream>>>(pooled, cntg, Wf1, bf1, Wf2, bf2, (float*)d_out);
}

// Round 3
// 610.568 us; speedup vs baseline: 1.9736x; 1.3937x over previous
//
#include <hip/hip_runtime.h>

#define N_NODES 50000
#define N_PAD   50048   // feature buffers padded to multiple of 64 rows
#define N_EDGES 800000
#define N_GRAPHS 64
#define D 90
#define S 96   // padded feature stride (floats)

// ---------------- CSR build ----------------
__global__ void k_count(const int* __restrict__ dst, int* __restrict__ cnt) {
    int e = blockIdx.x * 256 + threadIdx.x;
    if (e < N_EDGES) atomicAdd(&cnt[dst[e]], 1);
}

__global__ void k_scan1(const int* __restrict__ cnt, int* __restrict__ bsum) {
    __shared__ int s[256];
    int t = threadIdx.x;
    int i = blockIdx.x * 256 + t;
    s[t] = (i < N_NODES) ? cnt[i] : 0;
    __syncthreads();
    for (int o = 128; o > 0; o >>= 1) { if (t < o) s[t] += s[t + o]; __syncthreads(); }
    if (t == 0) bsum[blockIdx.x] = s[0];
}

__global__ void k_scan2(const int* __restrict__ bsum, int* __restrict__ bpre, int nb) {
    __shared__ int s[256];
    int t = threadIdx.x;
    int v = (t < nb) ? bsum[t] : 0;
    s[t] = v; __syncthreads();
    for (int o = 1; o < 256; o <<= 1) {
        int x = (t >= o) ? s[t - o] : 0;
        __syncthreads();
        s[t] += x;
        __syncthreads();
    }
    bpre[t] = s[t] - v;  // exclusive
}

__global__ void k_scan3(const int* __restrict__ cnt, const int* __restrict__ bpre,
                        int* __restrict__ off, int* __restrict__ cursor) {
    __shared__ int s[256];
    int t = threadIdx.x;
    int i = blockIdx.x * 256 + t;
    int v = (i < N_NODES) ? cnt[i] : 0;
    s[t] = v; __syncthreads();
    for (int o = 1; o < 256; o <<= 1) {
        int x = (t >= o) ? s[t - o] : 0;
        __syncthreads();
        s[t] += x;
        __syncthreads();
    }
    int excl = s[t] - v + bpre[blockIdx.x];
    if (i < N_NODES) { off[i] = excl; cursor[i] = excl; }
    if (i == N_NODES - 1) off[N_NODES] = excl + v;
}

__global__ void k_fill(const int* __restrict__ src, const int* __restrict__ dst,
                       int* __restrict__ cursor, int* __restrict__ csr) {
    int e = blockIdx.x * 256 + threadIdx.x;
    if (e >= N_EDGES) return;
    int p = atomicAdd(&cursor[dst[e]], 1);
    csr[p] = src[e];
}

// ---------------- W pad/pack: [layer][{l,r}][96 rows][100 floats], zero-padded ----------------
// Layout matches the LDS image read by k_gemm: row stride 25 float4 (100 floats).
__global__ void k_prepw(const float* __restrict__ w1l, const float* __restrict__ w1r,
                        const float* __restrict__ w2l, const float* __restrict__ w2r,
                        const float* __restrict__ w3l, const float* __restrict__ w3r,
                        float* __restrict__ Wpad) {
    int idx = blockIdx.x * 256 + threadIdx.x;
    const int per = 96 * 100;
    if (idx >= 6 * per) return;
    int slot = idx / per, rem = idx - slot * per;
    int j = rem / 100, k = rem - j * 100;
    const float* src;
    switch (slot) {
        case 0: src = w1l; break;
        case 1: src = w1r; break;
        case 2: src = w2l; break;
        case 3: src = w2r; break;
        case 4: src = w3l; break;
        default: src = w3r; break;
    }
    Wpad[idx] = (j < D && k < D) ? src[j * D + k] : 0.f;
}

// ---------------- mean aggregation: 1 wave per node ----------------
__global__ void k_agg(const float* __restrict__ hin, int hs,
                      const int* __restrict__ off, const int* __restrict__ csr,
                      float* __restrict__ outp) {
    int wid  = (blockIdx.x * 256 + threadIdx.x) >> 6;
    int lane = threadIdx.x & 63;
    if (wid >= N_NODES) return;
    int beg = off[wid], end = off[wid + 1];
    float a0 = 0.f, a1 = 0.f;
    for (int e = beg; e < end; ++e) {
        int sIdx = csr[e];
        const float* row = hin + sIdx * hs;
        a0 += row[lane];
        if (lane < D - 64) a1 += row[64 + lane];
    }
    float inv = 1.0f / fmaxf((float)(end - beg), 1.0f);
    outp[wid * S + lane] = a0 * inv;
    if (lane < 32) outp[wid * S + 64 + lane] = (lane < D - 64) ? a1 * inv : 0.f;
}

// ---------------- fused dual-GEMM + bias + ReLU, W resident in LDS ----------------
// out[n][j] = relu(bias[j] + sum_k agg[n][k]*Wl[j][k] + h[n][k]*Wr[j][k])
// LDS: Wl+Wr as [96][25] float4 each (stride 100 floats) = 76.8 KB -> 2 blocks/CU.
// Thread: 4 nodes (r0..r0+3) x 6 cols (j = cg + 16*jj). A/H stream global->reg.
template<int HS>
__global__ __launch_bounds__(256, 2) void k_gemm(
    const float* __restrict__ Apart,  // [N_PAD][S], pads zeroed (rows >= N_NODES garbage ok)
    const float* __restrict__ Hin,    // [N][HS]
    const float4* __restrict__ Wpad4, // 4800 float4: Wl then Wr, LDS image
    const float* __restrict__ bias,   // [D]
    float* __restrict__ outp)         // [N_PAD][S] (may alias Apart)
{
    extern __shared__ float4 Wlds[];  // [0,2400)=Wl, [2400,4800)=Wr
    int tid = threadIdx.x;
    #pragma unroll
    for (int t = 0; t < 19; ++t) {
        int idx = t * 256 + tid;
        if (idx < 4800) Wlds[idx] = Wpad4[idx];
    }
    __syncthreads();

    int w = tid >> 6, lane = tid & 63;
    int cg = lane & 15, ng = lane >> 4;
    int r0 = blockIdx.x * 64 + w * 16 + ng * 4;

    float acc[4][6];
    #pragma unroll
    for (int jj = 0; jj < 6; ++jj) {
        int j = cg + 16 * jj;
        float b = (j < D) ? bias[j] : 0.f;
        #pragma unroll
        for (int i = 0; i < 4; ++i) acc[i][jj] = b;
    }

    #pragma unroll 2
    for (int kc = 0; kc < 24; ++kc) {
        float4 a4[4], h4[4];
        #pragma unroll
        for (int i = 0; i < 4; ++i) {
            int n = r0 + i;
            a4[i] = *(const float4*)&Apart[n * S + kc * 4];
            if (HS == S) {
                h4[i] = *(const float4*)&Hin[n * S + kc * 4];
            } else {
                int nc = n < N_NODES ? n : N_NODES - 1;  // x is exactly [N_NODES][90]
                float2 lo = *(const float2*)&Hin[nc * HS + kc * 4];
                float2 hi = *(const float2*)&Hin[nc * HS + kc * 4 + 2];
                h4[i].x = lo.x; h4[i].y = lo.y; h4[i].z = hi.x; h4[i].w = hi.y;
            }
        }
        #pragma unroll
        for (int jj = 0; jj < 6; ++jj) {
            int j = cg + 16 * jj;
            float4 wlv = Wlds[j * 25 + kc];
            float4 wrv = Wlds[2400 + j * 25 + kc];
            #pragma unroll
            for (int i = 0; i < 4; ++i) {
                acc[i][jj] += a4[i].x * wlv.x + a4[i].y * wlv.y
                            + a4[i].z * wlv.z + a4[i].w * wlv.w
                            + h4[i].x * wrv.x + h4[i].y * wrv.y
                            + h4[i].z * wrv.z + h4[i].w * wrv.w;
            }
        }
    }

    #pragma unroll
    for (int i = 0; i < 4; ++i) {
        int n = r0 + i;
        if (n >= N_NODES) continue;
        #pragma unroll
        for (int jj = 0; jj < 6; ++jj) {
            int j = cg + 16 * jj;
            if (j < D) outp[n * S + j] = fmaxf(acc[i][jj], 0.f);
        }
    }
}

// ---------------- graph mean pool: segmented reduction (batch is sorted) ----------------
#define POOL_WAVES 512
__global__ void k_pool(const float* __restrict__ h, const int* __restrict__ batch,
                       float* __restrict__ pooled, float* __restrict__ cntg) {
    int wid  = (blockIdx.x * blockDim.x + threadIdx.x) >> 6;
    int lane = threadIdx.x & 63;
    const int per = (N_NODES + POOL_WAVES - 1) / POOL_WAVES;
    int beg = wid * per;
    int end = beg + per; if (end > N_NODES) end = N_NODES;
    if (beg >= end) return;
    int cur = batch[beg];
    float a0 = 0.f, a1 = 0.f, c = 0.f;
    for (int n = beg; n < end; ++n) {
        int g = batch[n];
        if (g != cur) {
            atomicAdd(&pooled[cur * D + lane], a0);
            if (lane < D - 64) atomicAdd(&pooled[cur * D + 64 + lane], a1);
            if (lane == 0) atomicAdd(&cntg[cur], c);
            a0 = a1 = c = 0.f;
            cur = g;
        }
        a0 += h[n * S + lane];
        if (lane < D - 64) a1 += h[n * S + 64 + lane];
        c += 1.f;
    }
    atomicAdd(&pooled[cur * D + lane], a0);
    if (lane < D - 64) atomicAdd(&pooled[cur * D + 64 + lane], a1);
    if (lane == 0) atomicAdd(&cntg[cur], c);
}

// ---------------- final MLP (single block) ----------------
__global__ void k_mlp(const float* __restrict__ pooled, const float* __restrict__ cntg,
                      const float* __restrict__ Wf1, const float* __restrict__ bf1,
                      const float* __restrict__ Wf2, const float* __restrict__ bf2,
                      float* __restrict__ outp) {
    __shared__ float P[N_GRAPHS][92];
    __shared__ float H4[N_GRAPHS][32];
    int tid = threadIdx.x;
    for (int idx = tid; idx < N_GRAPHS * D; idx += 256) {
        int g = idx / D, d = idx - g * D;
        P[g][d] = pooled[idx] / fmaxf(cntg[g], 1.0f);
    }
    __syncthreads();
    for (int idx = tid; idx < N_GRAPHS * 32; idx += 256) {
        int g = idx >> 5, c = idx & 31;
        float acc = bf1[c];
        for (int d = 0; d < D; ++d) acc += P[g][d] * Wf1[c * D + d];
        H4[g][c] = fmaxf(acc, 0.f);
    }
    __syncthreads();
    if (tid < N_GRAPHS) {
        float acc = bf2[0];
        #pragma unroll
        for (int c = 0; c < 32; ++c) acc += H4[tid][c] * Wf2[c];
        outp[tid] = acc;
    }
}

extern "C" void kernel_launch(void* const* d_in, const int* in_sizes, int n_in,
                              void* d_out, int out_size, void* d_ws, size_t ws_size,
                              hipStream_t stream) {
    const float* x    = (const float*)d_in[0];
    const int*   ei   = (const int*)d_in[1];
    const int*   batch= (const int*)d_in[2];
    const float* W1l  = (const float*)d_in[3];
    const float* b1   = (const float*)d_in[4];
    const float* W1r  = (const float*)d_in[5];
    const float* W2l  = (const float*)d_in[6];
    const float* b2   = (const float*)d_in[7];
    const float* W2r  = (const float*)d_in[8];
    const float* W3l  = (const float*)d_in[9];
    const float* b3   = (const float*)d_in[10];
    const float* W3r  = (const float*)d_in[11];
    const float* Wf1  = (const float*)d_in[12];
    const float* bf1  = (const float*)d_in[13];
    const float* Wf2  = (const float*)d_in[14];
    const float* bf2  = (const float*)d_in[15];
    const int* srcI = ei;
    const int* dstI = ei + N_EDGES;

    char* base = (char*)d_ws;
    size_t o = 0;
    auto alloc = [&](size_t bytes) -> void* {
        void* p = base + o;
        o = (o + bytes + 255) & ~(size_t)255;
        return p;
    };
    int*   cnt    = (int*)alloc((size_t)N_NODES * 4);
    int*   cursor = (int*)alloc((size_t)N_NODES * 4);
    int*   off    = (int*)alloc((size_t)(N_NODES + 1) * 4);
    int*   bsum   = (int*)alloc(256 * 4);
    int*   bpre   = (int*)alloc(256 * 4);
    int*   csr    = (int*)alloc((size_t)N_EDGES * 4);
    float* bufA   = (float*)alloc((size_t)N_PAD * S * 4);
    float* bufB   = (float*)alloc((size_t)N_PAD * S * 4);
    float* Wpad   = (float*)alloc((size_t)6 * 96 * 100 * 4);
    float* pooled = (float*)alloc((size_t)(N_GRAPHS * D + N_GRAPHS) * 4);
    float* cntg   = pooled + N_GRAPHS * D;

    // allow 76.8 KB dynamic LDS for both k_gemm instantiations
    const int WLDS_BYTES = 4800 * 16;
    hipFuncSetAttribute((const void*)k_gemm<D>, hipFuncAttributeMaxDynamicSharedMemorySize, WLDS_BYTES);
    hipFuncSetAttribute((const void*)k_gemm<S>, hipFuncAttributeMaxDynamicSharedMemorySize, WLDS_BYTES);

    hipMemsetAsync(cnt, 0, (size_t)N_NODES * 4, stream);
    hipMemsetAsync(pooled, 0, (size_t)(N_GRAPHS * D + N_GRAPHS) * 4, stream);

    const int NB = (N_NODES + 255) / 256;  // 196
    k_count<<<(N_EDGES + 255) / 256, 256, 0, stream>>>(dstI, cnt);
    k_scan1<<<NB, 256, 0, stream>>>(cnt, bsum);
    k_scan2<<<1, 256, 0, stream>>>(bsum, bpre, NB);
    k_scan3<<<NB, 256, 0, stream>>>(cnt, bpre, off, cursor);
    k_fill<<<(N_EDGES + 255) / 256, 256, 0, stream>>>(srcI, dstI, cursor, csr);
    k_prepw<<<(6 * 96 * 100 + 255) / 256, 256, 0, stream>>>(W1l, W1r, W2l, W2r, W3l, W3r, Wpad);

    const int AGG_BLOCKS  = N_NODES / 4;   // 12500 (4 waves/block, 1 node/wave)
    const int GEMM_BLOCKS = N_PAD / 64;    // 782

    const float4* Wp4 = (const float4*)Wpad;
    // layer 1
    k_agg<<<AGG_BLOCKS, 256, 0, stream>>>(x, D, off, csr, bufA);
    k_gemm<D><<<GEMM_BLOCKS, 256, WLDS_BYTES, stream>>>(bufA, x, Wp4, b1, bufA);
    // layer 2
    k_agg<<<AGG_BLOCKS, 256, 0, stream>>>(bufA, S, off, csr, bufB);
    k_gemm<S><<<GEMM_BLOCKS, 256, WLDS_BYTES, stream>>>(bufB, bufA, Wp4 + 4800, b2, bufB);
    // layer 3
    k_agg<<<AGG_BLOCKS, 256, 0, stream>>>(bufB, S, off, csr, bufA);
    k_gemm<S><<<GEMM_BLOCKS, 256, WLDS_BYTES, stream>>>(bufA, bufB, Wp4 + 9600, b3, bufA);

    k_pool<<<POOL_WAVES / 4, 256, 0, stream>>>(bufA, batch, pooled, cntg);
    k_mlp<<<1, 256, 0, stream>>>(pooled, cntg, Wf1, bf1, Wf2, bf2, (float*)d_out);
}

// Round 4
// 508.821 us; speedup vs baseline: 2.3682x; 1.2000x over previous
//
#include <hip/hip_runtime.h>
#include <hip/hip_bf16.h>

#define N_NODES 50000
#define N_PAD   50048   // feature buffers padded to multiple of 64 rows
#define N_EDGES 800000
#define N_GRAPHS 64
#define D 90
#define S 96   // padded feature stride (elements)

__device__ __forceinline__ float bflo(unsigned int v) { return __uint_as_float(v << 16); }
__device__ __forceinline__ float bfhi(unsigned int v) { return __uint_as_float(v & 0xffff0000u); }

// ---------------- CSR build ----------------
__global__ void k_count(const int* __restrict__ dst, int* __restrict__ cnt) {
    int e = blockIdx.x * 256 + threadIdx.x;
    if (e < N_EDGES) atomicAdd(&cnt[dst[e]], 1);
}

__global__ void k_scan1(const int* __restrict__ cnt, int* __restrict__ bsum) {
    __shared__ int s[256];
    int t = threadIdx.x;
    int i = blockIdx.x * 256 + t;
    s[t] = (i < N_NODES) ? cnt[i] : 0;
    __syncthreads();
    for (int o = 128; o > 0; o >>= 1) { if (t < o) s[t] += s[t + o]; __syncthreads(); }
    if (t == 0) bsum[blockIdx.x] = s[0];
}

__global__ void k_scan2(const int* __restrict__ bsum, int* __restrict__ bpre, int nb) {
    __shared__ int s[256];
    int t = threadIdx.x;
    int v = (t < nb) ? bsum[t] : 0;
    s[t] = v; __syncthreads();
    for (int o = 1; o < 256; o <<= 1) {
        int x = (t >= o) ? s[t - o] : 0;
        __syncthreads();
        s[t] += x;
        __syncthreads();
    }
    bpre[t] = s[t] - v;  // exclusive
}

__global__ void k_scan3(const int* __restrict__ cnt, const int* __restrict__ bpre,
                        int* __restrict__ off, int* __restrict__ cursor) {
    __shared__ int s[256];
    int t = threadIdx.x;
    int i = blockIdx.x * 256 + t;
    int v = (i < N_NODES) ? cnt[i] : 0;
    s[t] = v; __syncthreads();
    for (int o = 1; o < 256; o <<= 1) {
        int x = (t >= o) ? s[t - o] : 0;
        __syncthreads();
        s[t] += x;
        __syncthreads();
    }
    int excl = s[t] - v + bpre[blockIdx.x];
    if (i < N_NODES) { off[i] = excl; cursor[i] = excl; }
    if (i == N_NODES - 1) off[N_NODES] = excl + v;
}

__global__ void k_fill(const int* __restrict__ src, const int* __restrict__ dst,
                       int* __restrict__ cursor, int* __restrict__ csr) {
    int e = blockIdx.x * 256 + threadIdx.x;
    if (e >= N_EDGES) return;
    int p = atomicAdd(&cursor[dst[e]], 1);
    csr[p] = src[e];
}

// ---------------- W pad/pack: [layer][{l,r}][96 rows][100 floats], zero-padded ----------------
__global__ void k_prepw(const float* __restrict__ w1l, const float* __restrict__ w1r,
                        const float* __restrict__ w2l, const float* __restrict__ w2r,
                        const float* __restrict__ w3l, const float* __restrict__ w3r,
                        float* __restrict__ Wpad) {
    int idx = blockIdx.x * 256 + threadIdx.x;
    const int per = 96 * 100;
    if (idx >= 6 * per) return;
    int slot = idx / per, rem = idx - slot * per;
    int j = rem / 100, k = rem - j * 100;
    const float* src;
    switch (slot) {
        case 0: src = w1l; break;
        case 1: src = w1r; break;
        case 2: src = w2l; break;
        case 3: src = w2r; break;
        case 4: src = w3l; break;
        default: src = w3r; break;
    }
    Wpad[idx] = (j < D && k < D) ? src[j * D + k] : 0.f;
}

// ---------------- x f32 [N][90] -> bf16 [N_PAD][96], pads/tail zeroed ----------------
__global__ void k_cvt(const float* __restrict__ x, __hip_bfloat16* __restrict__ xb) {
    int idx = blockIdx.x * 256 + threadIdx.x;
    if (idx >= N_PAD * S) return;
    int n = idx / S, k = idx - n * S;
    float v = (n < N_NODES && k < D) ? x[n * D + k] : 0.f;
    xb[idx] = __float2bfloat16(v);
}

// ---------------- mean aggregation over bf16 features: 1 wave per node ----------------
// lane l (<48) covers elems {2l, 2l+1} via one dword load per edge; 2 edges in flight.
__global__ void k_agg(const __hip_bfloat16* __restrict__ hin,
                      const int* __restrict__ off, const int* __restrict__ csr,
                      float* __restrict__ outp) {
    int wid  = (blockIdx.x * 256 + threadIdx.x) >> 6;
    int lane = threadIdx.x & 63;
    if (wid >= N_NODES) return;
    int beg = off[wid], end = off[wid + 1];
    const unsigned int* base = (const unsigned int*)hin;  // row stride 48 dwords
    float a0 = 0.f, a1 = 0.f;
    int e = beg;
    for (; e + 1 < end; e += 2) {
        int s0 = csr[e], s1 = csr[e + 1];
        if (lane < 48) {
            unsigned int v0 = base[s0 * 48 + lane];
            unsigned int v1 = base[s1 * 48 + lane];
            a0 += bflo(v0) + bflo(v1);
            a1 += bfhi(v0) + bfhi(v1);
        }
    }
    if (e < end) {
        int s0 = csr[e];
        if (lane < 48) {
            unsigned int v0 = base[s0 * 48 + lane];
            a0 += bflo(v0);
            a1 += bfhi(v0);
        }
    }
    float inv = 1.0f / fmaxf((float)(end - beg), 1.0f);
    if (lane < 45) {
        *(float2*)&outp[wid * S + 2 * lane] = make_float2(a0 * inv, a1 * inv);
    } else if (lane < 48) {
        *(float2*)&outp[wid * S + 2 * lane] = make_float2(0.f, 0.f);  // pad cols 90..95
    }
}

// ---------------- fused dual-GEMM + bias + ReLU, W resident in LDS ----------------
// out[n][j] = relu(bias[j] + sum_k agg[n][k]*Wl[j][k] + h[n][k]*Wr[j][k])
// LDS: Wl+Wr as [96][25] float4 each = 76.8 KB -> 2 blocks/CU.
// A f32 stride S; H bf16 stride S; out bf16 stride S (pad cols zeroed).
__global__ __launch_bounds__(256, 2) void k_gemm(
    const float* __restrict__ Apart,          // [N_PAD][S] f32
    const __hip_bfloat16* __restrict__ Hin,   // [N_PAD][S] bf16
    const float4* __restrict__ Wpad4,         // 4800 float4: Wl then Wr
    const float* __restrict__ bias,           // [D]
    __hip_bfloat16* __restrict__ outp)        // [N_PAD][S] bf16
{
    extern __shared__ float4 Wlds[];  // [0,2400)=Wl, [2400,4800)=Wr
    int tid = threadIdx.x;
    #pragma unroll
    for (int t = 0; t < 19; ++t) {
        int idx = t * 256 + tid;
        if (idx < 4800) Wlds[idx] = Wpad4[idx];
    }
    __syncthreads();

    int w = tid >> 6, lane = tid & 63;
    int cg = lane & 15, ng = lane >> 4;
    int r0 = blockIdx.x * 64 + w * 16 + ng * 4;

    float acc[4][6];
    #pragma unroll
    for (int jj = 0; jj < 6; ++jj) {
        int j = cg + 16 * jj;
        float b = (j < D) ? bias[j] : 0.f;
        #pragma unroll
        for (int i = 0; i < 4; ++i) acc[i][jj] = b;
    }

    #pragma unroll 2
    for (int kc = 0; kc < 24; ++kc) {
        float4 a4[4], h4[4];
        #pragma unroll
        for (int i = 0; i < 4; ++i) {
            int n = r0 + i;
            a4[i] = *(const float4*)&Apart[n * S + kc * 4];
            ushort4 hu = *(const ushort4*)&Hin[n * S + kc * 4];
            h4[i].x = bflo(((unsigned int)hu.x));
            h4[i].y = bflo(((unsigned int)hu.y));
            h4[i].z = bflo(((unsigned int)hu.z));
            h4[i].w = bflo(((unsigned int)hu.w));
        }
        #pragma unroll
        for (int jj = 0; jj < 6; ++jj) {
            int j = cg + 16 * jj;
            float4 wlv = Wlds[j * 25 + kc];
            float4 wrv = Wlds[2400 + j * 25 + kc];
            #pragma unroll
            for (int i = 0; i < 4; ++i) {
                acc[i][jj] += a4[i].x * wlv.x + a4[i].y * wlv.y
                            + a4[i].z * wlv.z + a4[i].w * wlv.w
                            + h4[i].x * wrv.x + h4[i].y * wrv.y
                            + h4[i].z * wrv.z + h4[i].w * wrv.w;
            }
        }
    }

    #pragma unroll
    for (int i = 0; i < 4; ++i) {
        int n = r0 + i;
        if (n >= N_NODES) continue;
        #pragma unroll
        for (int jj = 0; jj < 6; ++jj) {
            int j = cg + 16 * jj;
            float v = (j < D) ? fmaxf(acc[i][jj], 0.f) : 0.f;
            outp[n * S + j] = __float2bfloat16(v);
        }
    }
}

// ---------------- graph mean pool: segmented reduction over bf16 h ----------------
#define POOL_WAVES 512
__global__ void k_pool(const __hip_bfloat16* __restrict__ h, const int* __restrict__ batch,
                       float* __restrict__ pooled, float* __restrict__ cntg) {
    int wid  = (blockIdx.x * blockDim.x + threadIdx.x) >> 6;
    int lane = threadIdx.x & 63;
    const int per = (N_NODES + POOL_WAVES - 1) / POOL_WAVES;
    int beg = wid * per;
    int end = beg + per; if (end > N_NODES) end = N_NODES;
    if (beg >= end) return;
    const unsigned int* base = (const unsigned int*)h;  // row stride 48 dwords
    int cur = batch[beg];
    float a0 = 0.f, a1 = 0.f, c = 0.f;
    for (int n = beg; n < end; ++n) {
        int g = batch[n];
        if (g != cur) {
            if (lane < 45) {
                atomicAdd(&pooled[cur * D + 2 * lane], a0);
                atomicAdd(&pooled[cur * D + 2 * lane + 1], a1);
            }
            if (lane == 0) atomicAdd(&cntg[cur], c);
            a0 = a1 = c = 0.f;
            cur = g;
        }
        if (lane < 45) {
            unsigned int v = base[n * 48 + lane];
            a0 += bflo(v);
            a1 += bfhi(v);
        }
        c += 1.f;
    }
    if (lane < 45) {
        atomicAdd(&pooled[cur * D + 2 * lane], a0);
        atomicAdd(&pooled[cur * D + 2 * lane + 1], a1);
    }
    if (lane == 0) atomicAdd(&cntg[cur], c);
}

// ---------------- final MLP (single block) ----------------
__global__ void k_mlp(const float* __restrict__ pooled, const float* __restrict__ cntg,
                      const float* __restrict__ Wf1, const float* __restrict__ bf1,
                      const float* __restrict__ Wf2, const float* __restrict__ bf2,
                      float* __restrict__ outp) {
    __shared__ float P[N_GRAPHS][92];
    __shared__ float H4[N_GRAPHS][32];
    int tid = threadIdx.x;
    for (int idx = tid; idx < N_GRAPHS * D; idx += 256) {
        int g = idx / D, d = idx - g * D;
        P[g][d] = pooled[idx] / fmaxf(cntg[g], 1.0f);
    }
    __syncthreads();
    for (int idx = tid; idx < N_GRAPHS * 32; idx += 256) {
        int g = idx >> 5, c = idx & 31;
        float acc = bf1[c];
        for (int d = 0; d < D; ++d) acc += P[g][d] * Wf1[c * D + d];
        H4[g][c] = fmaxf(acc, 0.f);
    }
    __syncthreads();
    if (tid < N_GRAPHS) {
        float acc = bf2[0];
        #pragma unroll
        for (int c = 0; c < 32; ++c) acc += H4[tid][c] * Wf2[c];
        outp[tid] = acc;
    }
}

extern "C" void kernel_launch(void* const* d_in, const int* in_sizes, int n_in,
                              void* d_out, int out_size, void* d_ws, size_t ws_size,
                              hipStream_t stream) {
    const float* x    = (const float*)d_in[0];
    const int*   ei   = (const int*)d_in[1];
    const int*   batch= (const int*)d_in[2];
    const float* W1l  = (const float*)d_in[3];
    const float* b1   = (const float*)d_in[4];
    const float* W1r  = (const float*)d_in[5];
    const float* W2l  = (const float*)d_in[6];
    const float* b2   = (const float*)d_in[7];
    const float* W2r  = (const float*)d_in[8];
    const float* W3l  = (const float*)d_in[9];
    const float* b3   = (const float*)d_in[10];
    const float* W3r  = (const float*)d_in[11];
    const float* Wf1  = (const float*)d_in[12];
    const float* bf1  = (const float*)d_in[13];
    const float* Wf2  = (const float*)d_in[14];
    const float* bf2  = (const float*)d_in[15];
    const int* srcI = ei;
    const int* dstI = ei + N_EDGES;

    char* base = (char*)d_ws;
    size_t o = 0;
    auto alloc = [&](size_t bytes) -> void* {
        void* p = base + o;
        o = (o + bytes + 255) & ~(size_t)255;
        return p;
    };
    int*   cnt    = (int*)alloc((size_t)N_NODES * 4);
    int*   cursor = (int*)alloc((size_t)N_NODES * 4);
    int*   off    = (int*)alloc((size_t)(N_NODES + 1) * 4);
    int*   bsum   = (int*)alloc(256 * 4);
    int*   bpre   = (int*)alloc(256 * 4);
    int*   csr    = (int*)alloc((size_t)N_EDGES * 4);
    __hip_bfloat16* xb = (__hip_bfloat16*)alloc((size_t)N_PAD * S * 2);
    __hip_bfloat16* hA = (__hip_bfloat16*)alloc((size_t)N_PAD * S * 2);
    __hip_bfloat16* hB = (__hip_bfloat16*)alloc((size_t)N_PAD * S * 2);
    float* aggF   = (float*)alloc((size_t)N_PAD * S * 4);
    float* Wpad   = (float*)alloc((size_t)6 * 96 * 100 * 4);
    float* pooled = (float*)alloc((size_t)(N_GRAPHS * D + N_GRAPHS) * 4);
    float* cntg   = pooled + N_GRAPHS * D;

    const int WLDS_BYTES = 4800 * 16;  // 76.8 KB
    hipFuncSetAttribute((const void*)k_gemm, hipFuncAttributeMaxDynamicSharedMemorySize, WLDS_BYTES);

    hipMemsetAsync(cnt, 0, (size_t)N_NODES * 4, stream);
    hipMemsetAsync(pooled, 0, (size_t)(N_GRAPHS * D + N_GRAPHS) * 4, stream);

    const int NB = (N_NODES + 255) / 256;  // 196
    k_count<<<(N_EDGES + 255) / 256, 256, 0, stream>>>(dstI, cnt);
    k_scan1<<<NB, 256, 0, stream>>>(cnt, bsum);
    k_scan2<<<1, 256, 0, stream>>>(bsum, bpre, NB);
    k_scan3<<<NB, 256, 0, stream>>>(cnt, bpre, off, cursor);
    k_fill<<<(N_EDGES + 255) / 256, 256, 0, stream>>>(srcI, dstI, cursor, csr);
    k_prepw<<<(6 * 96 * 100 + 255) / 256, 256, 0, stream>>>(W1l, W1r, W2l, W2r, W3l, W3r, Wpad);
    k_cvt<<<(N_PAD * S + 255) / 256, 256, 0, stream>>>(x, xb);

    const int AGG_BLOCKS  = N_NODES / 4;   // 12500 (4 waves/block, 1 node/wave)
    const int GEMM_BLOCKS = N_PAD / 64;    // 782

    const float4* Wp4 = (const float4*)Wpad;
    // layer 1
    k_agg<<<AGG_BLOCKS, 256, 0, stream>>>(xb, off, csr, aggF);
    k_gemm<<<GEMM_BLOCKS, 256, WLDS_BYTES, stream>>>(aggF, xb, Wp4, b1, hA);
    // layer 2
    k_agg<<<AGG_BLOCKS, 256, 0, stream>>>(hA, off, csr, aggF);
    k_gemm<<<GEMM_BLOCKS, 256, WLDS_BYTES, stream>>>(aggF, hA, Wp4 + 4800, b2, hB);
    // layer 3
    k_agg<<<AGG_BLOCKS, 256, 0, stream>>>(hB, off, csr, aggF);
    k_gemm<<<GEMM_BLOCKS, 256, WLDS_BYTES, stream>>>(aggF, hB, Wp4 + 9600, b3, hA);

    k_pool<<<POOL_WAVES / 4, 256, 0, stream>>>(hA, batch, pooled, cntg);
    k_mlp<<<1, 256, 0, stream>>>(pooled, cntg, Wf1, bf1, Wf2, bf2, (float*)d_out);
}

// Round 5
// 398.079 us; speedup vs baseline: 3.0270x; 1.2782x over previous
//
#include <hip/hip_runtime.h>
#include <hip/hip_bf16.h>

#define N_NODES 50000
#define N_PAD   50048   // padded to multiple of 64 rows
#define N_EDGES 800000
#define N_GRAPHS 64
#define D 90
#define SC  192   // cat row stride, bf16 elems: [agg(96) | h(96)]
#define SCD 96    // cat row stride in dwords

typedef __attribute__((ext_vector_type(8))) short bf16x8;
typedef __attribute__((ext_vector_type(4))) float f32x4;

__device__ __forceinline__ float bflo(unsigned int v) { return __uint_as_float(v << 16); }
__device__ __forceinline__ float bfhi(unsigned int v) { return __uint_as_float(v & 0xffff0000u); }
__device__ __forceinline__ unsigned short bf16bits(float f) {
    __hip_bfloat16 b = __float2bfloat16(f);
    return *(unsigned short*)&b;
}
__device__ __forceinline__ unsigned int pack2bf(float lo, float hi) {
    return (unsigned int)bf16bits(lo) | ((unsigned int)bf16bits(hi) << 16);
}

// ---------------- CSR build ----------------
__global__ void k_count(const int* __restrict__ dst, int* __restrict__ cnt) {
    int e = blockIdx.x * 256 + threadIdx.x;
    if (e < N_EDGES) atomicAdd(&cnt[dst[e]], 1);
}

__global__ void k_scan1(const int* __restrict__ cnt, int* __restrict__ bsum) {
    __shared__ int s[256];
    int t = threadIdx.x;
    int i = blockIdx.x * 256 + t;
    s[t] = (i < N_NODES) ? cnt[i] : 0;
    __syncthreads();
    for (int o = 128; o > 0; o >>= 1) { if (t < o) s[t] += s[t + o]; __syncthreads(); }
    if (t == 0) bsum[blockIdx.x] = s[0];
}

__global__ void k_scan2(const int* __restrict__ bsum, int* __restrict__ bpre, int nb) {
    __shared__ int s[256];
    int t = threadIdx.x;
    int v = (t < nb) ? bsum[t] : 0;
    s[t] = v; __syncthreads();
    for (int o = 1; o < 256; o <<= 1) {
        int x = (t >= o) ? s[t - o] : 0;
        __syncthreads();
        s[t] += x;
        __syncthreads();
    }
    bpre[t] = s[t] - v;  // exclusive
}

__global__ void k_scan3(const int* __restrict__ cnt, const int* __restrict__ bpre,
                        int* __restrict__ off, int* __restrict__ cursor) {
    __shared__ int s[256];
    int t = threadIdx.x;
    int i = blockIdx.x * 256 + t;
    int v = (i < N_NODES) ? cnt[i] : 0;
    s[t] = v; __syncthreads();
    for (int o = 1; o < 256; o <<= 1) {
        int x = (t >= o) ? s[t - o] : 0;
        __syncthreads();
        s[t] += x;
        __syncthreads();
    }
    int excl = s[t] - v + bpre[blockIdx.x];
    if (i < N_NODES) { off[i] = excl; cursor[i] = excl; }
    if (i == N_NODES - 1) off[N_NODES] = excl + v;
}

__global__ void k_fill(const int* __restrict__ src, const int* __restrict__ dst,
                       int* __restrict__ cursor, int* __restrict__ csr) {
    int e = blockIdx.x * 256 + threadIdx.x;
    if (e >= N_EDGES) return;
    int p = atomicAdd(&cursor[dst[e]], 1);
    csr[p] = src[e];
}

// ---------------- Wcat: [3 layers][96 j][192 k] bf16, row j = [Wl[j](pad96) | Wr[j](pad96)] ----------------
__global__ void k_prepw(const float* __restrict__ w1l, const float* __restrict__ w1r,
                        const float* __restrict__ w2l, const float* __restrict__ w2r,
                        const float* __restrict__ w3l, const float* __restrict__ w3r,
                        __hip_bfloat16* __restrict__ Wcat) {
    int idx = blockIdx.x * 256 + threadIdx.x;
    const int per = 96 * SC;
    if (idx >= 3 * per) return;
    int layer = idx / per, rem = idx - layer * per;
    int j = rem / SC, k = rem - j * SC;
    const float* wl = (layer == 0) ? w1l : (layer == 1) ? w2l : w3l;
    const float* wr = (layer == 0) ? w1r : (layer == 1) ? w2r : w3r;
    float v = 0.f;
    if (j < D) {
        if (k < 96) { if (k < D) v = wl[j * D + k]; }
        else        { int kk = k - 96; if (kk < D) v = wr[j * D + kk]; }
    }
    Wcat[idx] = __float2bfloat16(v);
}

// ---------------- x f32 [N][90] -> cat h-region (cols 96..191) bf16, pads zeroed ----------------
__global__ void k_cvt(const float* __restrict__ x, __hip_bfloat16* __restrict__ cat) {
    int idx = blockIdx.x * 256 + threadIdx.x;  // over N_PAD*96 (h-region elems)
    if (idx >= N_PAD * 96) return;
    int n = idx / 96, k = idx - n * 96;
    float v = (n < N_NODES && k < D) ? x[n * D + k] : 0.f;
    cat[n * SC + 96 + k] = __float2bfloat16(v);
}

// ---------------- mean aggregation: 1 wave per node, in-place into cat cols 0..95 ----------------
// reads h at dword 48+lane of each source row; writes agg at dword lane of own row.
__global__ void k_agg(unsigned int* __restrict__ cat,
                      const int* __restrict__ off, const int* __restrict__ csr) {
    int wid  = (blockIdx.x * 256 + threadIdx.x) >> 6;
    int lane = threadIdx.x & 63;
    if (wid >= N_NODES) return;
    int beg = off[wid], end = off[wid + 1];
    float a0 = 0.f, a1 = 0.f;
    int e = beg;
    for (; e + 1 < end; e += 2) {
        int s0 = csr[e], s1 = csr[e + 1];
        if (lane < 48) {
            unsigned int v0 = cat[s0 * SCD + 48 + lane];
            unsigned int v1 = cat[s1 * SCD + 48 + lane];
            a0 += bflo(v0) + bflo(v1);
            a1 += bfhi(v0) + bfhi(v1);
        }
    }
    if (e < end && lane < 48) {
        unsigned int v0 = cat[csr[e] * SCD + 48 + lane];
        a0 += bflo(v0);
        a1 += bfhi(v0);
    }
    float inv = 1.0f / fmaxf((float)(end - beg), 1.0f);
    if (lane < 48) {
        bool valid = (lane < 45);   // cols 90..95 are pad
        cat[wid * SCD + lane] = valid ? pack2bf(a0 * inv, a1 * inv) : 0u;
    }
}

// ---------------- MFMA dual-GEMM + bias + ReLU ----------------
// Hout[n][96+j] = relu(bias[j] + sum_{k<192} Acat[n][k] * Wcat[j][k])
// block = 64 nodes x 96 cols; wave w owns 16-row strip; 6 col-tiles x 6 k-steps MFMA.
__global__ __launch_bounds__(256) void k_gemm(
    const __hip_bfloat16* __restrict__ Acat,  // [N_PAD][192]
    const __hip_bfloat16* __restrict__ Wcat,  // [96][192]
    const float* __restrict__ bias,           // [90]
    __hip_bfloat16* __restrict__ Hout)        // [N_PAD][192], writes cols 96..191
{
    __shared__ float biasPad[96];
    int tid = threadIdx.x;
    if (tid < 96) biasPad[tid] = (tid < D) ? bias[tid] : 0.f;
    __syncthreads();

    int w = tid >> 6, lane = tid & 63;
    int r0 = blockIdx.x * 64 + w * 16;
    int mrow = lane & 15, kg = lane >> 4;   // A row within tile; k-group 0..3

    const short* A = (const short*)Acat;
    const short* W = (const short*)Wcat;

    f32x4 acc[6];
    #pragma unroll
    for (int t = 0; t < 6; ++t) {
        float b = biasPad[t * 16 + mrow];   // C col = lane&15
        acc[t] = (f32x4){b, b, b, b};
    }

    #pragma unroll
    for (int ks = 0; ks < 6; ++ks) {
        bf16x8 a = *(const bf16x8*)&A[(r0 + mrow) * SC + ks * 32 + kg * 8];
        #pragma unroll
        for (int t = 0; t < 6; ++t) {
            bf16x8 bfr = *(const bf16x8*)&W[(t * 16 + mrow) * SC + ks * 32 + kg * 8];
            acc[t] = __builtin_amdgcn_mfma_f32_16x16x32_bf16(a, bfr, acc[t], 0, 0, 0);
        }
    }

    // C/D layout (m89): col = lane&15, row = (lane>>4)*4 + v
    int orow = r0 + kg * 4;
    #pragma unroll
    for (int t = 0; t < 6; ++t) {
        int j = t * 16 + mrow;
        #pragma unroll
        for (int v = 0; v < 4; ++v) {
            float val = (j < D) ? fmaxf(acc[t][v], 0.f) : 0.f;
            Hout[(orow + v) * SC + 96 + j] = __float2bfloat16(val);
        }
    }
}

// ---------------- graph mean pool: segmented reduction (batch sorted) ----------------
#define POOL_WAVES 512
__global__ void k_pool(const unsigned int* __restrict__ cat, const int* __restrict__ batch,
                       float* __restrict__ pooled, float* __restrict__ cntg) {
    int wid  = (blockIdx.x * blockDim.x + threadIdx.x) >> 6;
    int lane = threadIdx.x & 63;
    const int per = (N_NODES + POOL_WAVES - 1) / POOL_WAVES;
    int beg = wid * per;
    int end = beg + per; if (end > N_NODES) end = N_NODES;
    if (beg >= end) return;
    int cur = batch[beg];
    float a0 = 0.f, a1 = 0.f, c = 0.f;
    for (int n = beg; n < end; ++n) {
        int g = batch[n];
        if (g != cur) {
            if (lane < 45) {
                atomicAdd(&pooled[cur * D + 2 * lane], a0);
                atomicAdd(&pooled[cur * D + 2 * lane + 1], a1);
            }
            if (lane == 0) atomicAdd(&cntg[cur], c);
            a0 = a1 = c = 0.f;
            cur = g;
        }
        if (lane < 45) {
            unsigned int v = cat[n * SCD + 48 + lane];
            a0 += bflo(v);
            a1 += bfhi(v);
        }
        c += 1.f;
    }
    if (lane < 45) {
        atomicAdd(&pooled[cur * D + 2 * lane], a0);
        atomicAdd(&pooled[cur * D + 2 * lane + 1], a1);
    }
    if (lane == 0) atomicAdd(&cntg[cur], c);
}

// ---------------- final MLP (single block) ----------------
__global__ void k_mlp(const float* __restrict__ pooled, const float* __restrict__ cntg,
                      const float* __restrict__ Wf1, const float* __restrict__ bf1,
                      const float* __restrict__ Wf2, const float* __restrict__ bf2,
                      float* __restrict__ outp) {
    __shared__ float P[N_GRAPHS][92];
    __shared__ float H4[N_GRAPHS][32];
    int tid = threadIdx.x;
    for (int idx = tid; idx < N_GRAPHS * D; idx += 256) {
        int g = idx / D, d = idx - g * D;
        P[g][d] = pooled[idx] / fmaxf(cntg[g], 1.0f);
    }
    __syncthreads();
    for (int idx = tid; idx < N_GRAPHS * 32; idx += 256) {
        int g = idx >> 5, c = idx & 31;
        float acc = bf1[c];
        for (int d = 0; d < D; ++d) acc += P[g][d] * Wf1[c * D + d];
        H4[g][c] = fmaxf(acc, 0.f);
    }
    __syncthreads();
    if (tid < N_GRAPHS) {
        float acc = bf2[0];
        #pragma unroll
        for (int c = 0; c < 32; ++c) acc += H4[tid][c] * Wf2[c];
        outp[tid] = acc;
    }
}

extern "C" void kernel_launch(void* const* d_in, const int* in_sizes, int n_in,
                              void* d_out, int out_size, void* d_ws, size_t ws_size,
                              hipStream_t stream) {
    const float* x    = (const float*)d_in[0];
    const int*   ei   = (const int*)d_in[1];
    const int*   batch= (const int*)d_in[2];
    const float* W1l  = (const float*)d_in[3];
    const float* b1   = (const float*)d_in[4];
    const float* W1r  = (const float*)d_in[5];
    const float* W2l  = (const float*)d_in[6];
    const float* b2   = (const float*)d_in[7];
    const float* W2r  = (const float*)d_in[8];
    const float* W3l  = (const float*)d_in[9];
    const float* b3   = (const float*)d_in[10];
    const float* W3r  = (const float*)d_in[11];
    const float* Wf1  = (const float*)d_in[12];
    const float* bf1  = (const float*)d_in[13];
    const float* Wf2  = (const float*)d_in[14];
    const float* bf2  = (const float*)d_in[15];
    const int* srcI = ei;
    const int* dstI = ei + N_EDGES;

    char* base = (char*)d_ws;
    size_t o = 0;
    auto alloc = [&](size_t bytes) -> void* {
        void* p = base + o;
        o = (o + bytes + 255) & ~(size_t)255;
        return p;
    };
    int*   cnt    = (int*)alloc((size_t)N_NODES * 4);
    int*   cursor = (int*)alloc((size_t)N_NODES * 4);
    int*   off    = (int*)alloc((size_t)(N_NODES + 1) * 4);
    int*   bsum   = (int*)alloc(256 * 4);
    int*   bpre   = (int*)alloc(256 * 4);
    int*   csr    = (int*)alloc((size_t)N_EDGES * 4);
    __hip_bfloat16* catA = (__hip_bfloat16*)alloc((size_t)N_PAD * SC * 2);
    __hip_bfloat16* catB = (__hip_bfloat16*)alloc((size_t)N_PAD * SC * 2);
    __hip_bfloat16* Wcat = (__hip_bfloat16*)alloc((size_t)3 * 96 * SC * 2);
    float* pooled = (float*)alloc((size_t)(N_GRAPHS * D + N_GRAPHS) * 4);
    float* cntg   = pooled + N_GRAPHS * D;

    hipMemsetAsync(cnt, 0, (size_t)N_NODES * 4, stream);
    hipMemsetAsync(pooled, 0, (size_t)(N_GRAPHS * D + N_GRAPHS) * 4, stream);

    const int NB = (N_NODES + 255) / 256;  // 196
    k_count<<<(N_EDGES + 255) / 256, 256, 0, stream>>>(dstI, cnt);
    k_scan1<<<NB, 256, 0, stream>>>(cnt, bsum);
    k_scan2<<<1, 256, 0, stream>>>(bsum, bpre, NB);
    k_scan3<<<NB, 256, 0, stream>>>(cnt, bpre, off, cursor);
    k_fill<<<(N_EDGES + 255) / 256, 256, 0, stream>>>(srcI, dstI, cursor, csr);
    k_prepw<<<(3 * 96 * SC + 255) / 256, 256, 0, stream>>>(W1l, W1r, W2l, W2r, W3l, W3r, Wcat);
    k_cvt<<<(N_PAD * 96 + 255) / 256, 256, 0, stream>>>(x, catA);

    const int AGG_BLOCKS  = N_NODES / 4;   // 12500 (4 waves/block, 1 node/wave)
    const int GEMM_BLOCKS = N_PAD / 64;    // 782

    unsigned int* catAu = (unsigned int*)catA;
    unsigned int* catBu = (unsigned int*)catB;

    // layer 1: agg(x) into catA cols 0..95; gemm catA -> catB h-region
    k_agg<<<AGG_BLOCKS, 256, 0, stream>>>(catAu, off, csr);
    k_gemm<<<GEMM_BLOCKS, 256, 0, stream>>>(catA, Wcat, b1, catB);
    // layer 2
    k_agg<<<AGG_BLOCKS, 256, 0, stream>>>(catBu, off, csr);
    k_gemm<<<GEMM_BLOCKS, 256, 0, stream>>>(catB, Wcat + 96 * SC, b2, catA);
    // layer 3
    k_agg<<<AGG_BLOCKS, 256, 0, stream>>>(catAu, off, csr);
    k_gemm<<<GEMM_BLOCKS, 256, 0, stream>>>(catA, Wcat + 2 * 96 * SC, b3, catB);

    k_pool<<<POOL_WAVES / 4, 256, 0, stream>>>(catBu, batch, pooled, cntg);
    k_mlp<<<1, 256, 0, stream>>>(pooled, cntg, Wf1, bf1, Wf2, bf2, (float*)d_out);
}

// Round 6
// 327.149 us; speedup vs baseline: 3.6833x; 1.2168x over previous
//
#include <hip/hip_runtime.h>
#include <hip/hip_bf16.h>

#define N_NODES 50000
#define N_PAD   50048   // padded to multiple of 64 rows
#define N_EDGES 800000
#define N_GRAPHS 64
#define D 90
#define SC  192   // cat row stride, bf16 elems: [agg(96) | h(96)]
#define SCD 96    // cat row stride in dwords

typedef __attribute__((ext_vector_type(8))) short bf16x8;
typedef __attribute__((ext_vector_type(4))) float f32x4;

__device__ __forceinline__ float bflo(unsigned int v) { return __uint_as_float(v << 16); }
__device__ __forceinline__ float bfhi(unsigned int v) { return __uint_as_float(v & 0xffff0000u); }
__device__ __forceinline__ unsigned short bf16bits(float f) {
    __hip_bfloat16 b = __float2bfloat16(f);
    return *(unsigned short*)&b;
}
__device__ __forceinline__ unsigned int pack2bf(float lo, float hi) {
    return (unsigned int)bf16bits(lo) | ((unsigned int)bf16bits(hi) << 16);
}

// ---------------- CSR build ----------------
__global__ void k_count(const int* __restrict__ dst, int* __restrict__ cnt) {
    int e = blockIdx.x * 256 + threadIdx.x;
    if (e < N_EDGES) atomicAdd(&cnt[dst[e]], 1);
}

__global__ void k_scan1(const int* __restrict__ cnt, int* __restrict__ bsum) {
    __shared__ int s[256];
    int t = threadIdx.x;
    int i = blockIdx.x * 256 + t;
    s[t] = (i < N_NODES) ? cnt[i] : 0;
    __syncthreads();
    for (int o = 128; o > 0; o >>= 1) { if (t < o) s[t] += s[t + o]; __syncthreads(); }
    if (t == 0) bsum[blockIdx.x] = s[0];
}

__global__ void k_scan2(const int* __restrict__ bsum, int* __restrict__ bpre, int nb) {
    __shared__ int s[256];
    int t = threadIdx.x;
    int v = (t < nb) ? bsum[t] : 0;
    s[t] = v; __syncthreads();
    for (int o = 1; o < 256; o <<= 1) {
        int x = (t >= o) ? s[t - o] : 0;
        __syncthreads();
        s[t] += x;
        __syncthreads();
    }
    bpre[t] = s[t] - v;  // exclusive
}

__global__ void k_scan3(const int* __restrict__ cnt, const int* __restrict__ bpre,
                        int* __restrict__ off, int* __restrict__ cursor) {
    __shared__ int s[256];
    int t = threadIdx.x;
    int i = blockIdx.x * 256 + t;
    int v = (i < N_NODES) ? cnt[i] : 0;
    s[t] = v; __syncthreads();
    for (int o = 1; o < 256; o <<= 1) {
        int x = (t >= o) ? s[t - o] : 0;
        __syncthreads();
        s[t] += x;
        __syncthreads();
    }
    int excl = s[t] - v + bpre[blockIdx.x];
    if (i < N_NODES) { off[i] = excl; cursor[i] = excl; }
    if (i == N_NODES - 1) off[N_NODES] = excl + v;
}

__global__ void k_fill(const int* __restrict__ src, const int* __restrict__ dst,
                       int* __restrict__ cursor, int* __restrict__ csr) {
    int e = blockIdx.x * 256 + threadIdx.x;
    if (e >= N_EDGES) return;
    int p = atomicAdd(&cursor[dst[e]], 1);
    csr[p] = src[e];
}

// ---------------- Wcat: [3 layers][96 j][192 k] bf16, row j = [Wl[j](pad96) | Wr[j](pad96)] ----------------
__global__ void k_prepw(const float* __restrict__ w1l, const float* __restrict__ w1r,
                        const float* __restrict__ w2l, const float* __restrict__ w2r,
                        const float* __restrict__ w3l, const float* __restrict__ w3r,
                        __hip_bfloat16* __restrict__ Wcat) {
    int idx = blockIdx.x * 256 + threadIdx.x;
    const int per = 96 * SC;
    if (idx >= 3 * per) return;
    int layer = idx / per, rem = idx - layer * per;
    int j = rem / SC, k = rem - j * SC;
    const float* wl = (layer == 0) ? w1l : (layer == 1) ? w2l : w3l;
    const float* wr = (layer == 0) ? w1r : (layer == 1) ? w2r : w3r;
    float v = 0.f;
    if (j < D) {
        if (k < 96) { if (k < D) v = wl[j * D + k]; }
        else        { int kk = k - 96; if (kk < D) v = wr[j * D + kk]; }
    }
    Wcat[idx] = __float2bfloat16(v);
}

// ---------------- x f32 [N][90] -> cat h-region (cols 96..191) bf16, pads zeroed ----------------
__global__ void k_cvt(const float* __restrict__ x, __hip_bfloat16* __restrict__ cat) {
    int idx = blockIdx.x * 256 + threadIdx.x;  // over N_PAD*96 (h-region elems)
    if (idx >= N_PAD * 96) return;
    int n = idx / 96, k = idx - n * 96;
    float v = (n < N_NODES && k < D) ? x[n * D + k] : 0.f;
    cat[n * SC + 96 + k] = __float2bfloat16(v);
}

// ---------------- mean aggregation: 1 wave per node, 16 lanes/edge, 4 edges/step, x2 unroll ----------------
// lane = (eg = lane>>4, sl = lane&15): loads dwords [48 + 3*sl, 48 + 3*sl + 3) of source row.
// After the loop, shfl_xor(16|32) folds the 4 edge groups; lanes 0..15 write the agg region.
__global__ void k_agg(unsigned int* __restrict__ cat,
                      const int* __restrict__ off, const int* __restrict__ csr) {
    int wid  = (blockIdx.x * 256 + threadIdx.x) >> 6;
    int lane = threadIdx.x & 63;
    if (wid >= N_NODES) return;
    int beg = off[wid], end = off[wid + 1];
    int eg = lane >> 4, sl = lane & 15;
    int col = 48 + 3 * sl;

    float a0 = 0.f, a1 = 0.f, a2 = 0.f, a3 = 0.f, a4 = 0.f, a5 = 0.f;
    int e = beg + eg;
    for (; e + 4 < end; e += 8) {
        int sA = csr[e], sB = csr[e + 4];
        const unsigned int* pA = &cat[sA * SCD + col];
        const unsigned int* pB = &cat[sB * SCD + col];
        unsigned int u0 = pA[0], u1 = pA[1], u2 = pA[2];
        unsigned int v0 = pB[0], v1 = pB[1], v2 = pB[2];
        a0 += bflo(u0) + bflo(v0); a1 += bfhi(u0) + bfhi(v0);
        a2 += bflo(u1) + bflo(v1); a3 += bfhi(u1) + bfhi(v1);
        a4 += bflo(u2) + bflo(v2); a5 += bfhi(u2) + bfhi(v2);
    }
    if (e < end) {
        const unsigned int* pA = &cat[csr[e] * SCD + col];
        unsigned int u0 = pA[0], u1 = pA[1], u2 = pA[2];
        a0 += bflo(u0); a1 += bfhi(u0);
        a2 += bflo(u1); a3 += bfhi(u1);
        a4 += bflo(u2); a5 += bfhi(u2);
    }

    // fold edge groups: lanes differing in bits 4,5 hold same sl
    #pragma unroll
    for (int m = 16; m <= 32; m <<= 1) {
        a0 += __shfl_xor(a0, m);
        a1 += __shfl_xor(a1, m);
        a2 += __shfl_xor(a2, m);
        a3 += __shfl_xor(a3, m);
        a4 += __shfl_xor(a4, m);
        a5 += __shfl_xor(a5, m);
    }

    if (eg == 0) {
        float inv = 1.0f / fmaxf((float)(end - beg), 1.0f);
        bool pad = (sl == 15);  // elems 90..95
        unsigned int* q = &cat[wid * SCD + 3 * sl];
        q[0] = pad ? 0u : pack2bf(a0 * inv, a1 * inv);
        q[1] = pad ? 0u : pack2bf(a2 * inv, a3 * inv);
        q[2] = pad ? 0u : pack2bf(a4 * inv, a5 * inv);
    }
}

// ---------------- MFMA dual-GEMM + bias + ReLU ----------------
// Hout[n][96+j] = relu(bias[j] + sum_{k<192} Acat[n][k] * Wcat[j][k])
// block = 64 nodes x 96 cols; wave w owns 16-row strip; 6 col-tiles x 6 k-steps MFMA.
__global__ __launch_bounds__(256) void k_gemm(
    const __hip_bfloat16* __restrict__ Acat,  // [N_PAD][192]
    const __hip_bfloat16* __restrict__ Wcat,  // [96][192]
    const float* __restrict__ bias,           // [90]
    __hip_bfloat16* __restrict__ Hout)        // [N_PAD][192], writes cols 96..191
{
    __shared__ float biasPad[96];
    int tid = threadIdx.x;
    if (tid < 96) biasPad[tid] = (tid < D) ? bias[tid] : 0.f;
    __syncthreads();

    int w = tid >> 6, lane = tid & 63;
    int r0 = blockIdx.x * 64 + w * 16;
    int mrow = lane & 15, kg = lane >> 4;   // A row within tile; k-group 0..3

    const short* A = (const short*)Acat;
    const short* W = (const short*)Wcat;

    f32x4 acc[6];
    #pragma unroll
    for (int t = 0; t < 6; ++t) {
        float b = biasPad[t * 16 + mrow];   // C col = lane&15
        acc[t] = (f32x4){b, b, b, b};
    }

    #pragma unroll
    for (int ks = 0; ks < 6; ++ks) {
        bf16x8 a = *(const bf16x8*)&A[(r0 + mrow) * SC + ks * 32 + kg * 8];
        #pragma unroll
        for (int t = 0; t < 6; ++t) {
            bf16x8 bfr = *(const bf16x8*)&W[(t * 16 + mrow) * SC + ks * 32 + kg * 8];
            acc[t] = __builtin_amdgcn_mfma_f32_16x16x32_bf16(a, bfr, acc[t], 0, 0, 0);
        }
    }

    // C/D layout (m89): col = lane&15, row = (lane>>4)*4 + v
    int orow = r0 + kg * 4;
    #pragma unroll
    for (int t = 0; t < 6; ++t) {
        int j = t * 16 + mrow;
        #pragma unroll
        for (int v = 0; v < 4; ++v) {
            float val = (j < D) ? fmaxf(acc[t][v], 0.f) : 0.f;
            Hout[(orow + v) * SC + 96 + j] = __float2bfloat16(val);
        }
    }
}

// ---------------- graph mean pool: segmented reduction (batch sorted) ----------------
#define POOL_WAVES 512
__global__ void k_pool(const unsigned int* __restrict__ cat, const int* __restrict__ batch,
                       float* __restrict__ pooled, float* __restrict__ cntg) {
    int wid  = (blockIdx.x * blockDim.x + threadIdx.x) >> 6;
    int lane = threadIdx.x & 63;
    const int per = (N_NODES + POOL_WAVES - 1) / POOL_WAVES;
    int beg = wid * per;
    int end = beg + per; if (end > N_NODES) end = N_NODES;
    if (beg >= end) return;
    int cur = batch[beg];
    float a0 = 0.f, a1 = 0.f, c = 0.f;
    for (int n = beg; n < end; ++n) {
        int g = batch[n];
        if (g != cur) {
            if (lane < 45) {
                atomicAdd(&pooled[cur * D + 2 * lane], a0);
                atomicAdd(&pooled[cur * D + 2 * lane + 1], a1);
            }
            if (lane == 0) atomicAdd(&cntg[cur], c);
            a0 = a1 = c = 0.f;
            cur = g;
        }
        if (lane < 45) {
            unsigned int v = cat[n * SCD + 48 + lane];
            a0 += bflo(v);
            a1 += bfhi(v);
        }
        c += 1.f;
    }
    if (lane < 45) {
        atomicAdd(&pooled[cur * D + 2 * lane], a0);
        atomicAdd(&pooled[cur * D + 2 * lane + 1], a1);
    }
    if (lane == 0) atomicAdd(&cntg[cur], c);
}

// ---------------- final MLP (single block) ----------------
__global__ void k_mlp(const float* __restrict__ pooled, const float* __restrict__ cntg,
                      const float* __restrict__ Wf1, const float* __restrict__ bf1,
                      const float* __restrict__ Wf2, const float* __restrict__ bf2,
                      float* __restrict__ outp) {
    __shared__ float P[N_GRAPHS][92];
    __shared__ float H4[N_GRAPHS][32];
    int tid = threadIdx.x;
    for (int idx = tid; idx < N_GRAPHS * D; idx += 256) {
        int g = idx / D, d = idx - g * D;
        P[g][d] = pooled[idx] / fmaxf(cntg[g], 1.0f);
    }
    __syncthreads();
    for (int idx = tid; idx < N_GRAPHS * 32; idx += 256) {
        int g = idx >> 5, c = idx & 31;
        float acc = bf1[c];
        for (int d = 0; d < D; ++d) acc += P[g][d] * Wf1[c * D + d];
        H4[g][c] = fmaxf(acc, 0.f);
    }
    __syncthreads();
    if (tid < N_GRAPHS) {
        float acc = bf2[0];
        #pragma unroll
        for (int c = 0; c < 32; ++c) acc += H4[tid][c] * Wf2[c];
        outp[tid] = acc;
    }
}

extern "C" void kernel_launch(void* const* d_in, const int* in_sizes, int n_in,
                              void* d_out, int out_size, void* d_ws, size_t ws_size,
                              hipStream_t stream) {
    const float* x    = (const float*)d_in[0];
    const int*   ei   = (const int*)d_in[1];
    const int*   batch= (const int*)d_in[2];
    const float* W1l  = (const float*)d_in[3];
    const float* b1   = (const float*)d_in[4];
    const float* W1r  = (const float*)d_in[5];
    const float* W2l  = (const float*)d_in[6];
    const float* b2   = (const float*)d_in[7];
    const float* W2r  = (const float*)d_in[8];
    const float* W3l  = (const float*)d_in[9];
    const float* b3   = (const float*)d_in[10];
    const float* W3r  = (const float*)d_in[11];
    const float* Wf1  = (const float*)d_in[12];
    const float* bf1  = (const float*)d_in[13];
    const float* Wf2  = (const float*)d_in[14];
    const float* bf2  = (const float*)d_in[15];
    const int* srcI = ei;
    const int* dstI = ei + N_EDGES;

    char* base = (char*)d_ws;
    size_t o = 0;
    auto alloc = [&](size_t bytes) -> void* {
        void* p = base + o;
        o = (o + bytes + 255) & ~(size_t)255;
        return p;
    };
    int*   cnt    = (int*)alloc((size_t)N_NODES * 4);
    int*   cursor = (int*)alloc((size_t)N_NODES * 4);
    int*   off    = (int*)alloc((size_t)(N_NODES + 1) * 4);
    int*   bsum   = (int*)alloc(256 * 4);
    int*   bpre   = (int*)alloc(256 * 4);
    int*   csr    = (int*)alloc((size_t)N_EDGES * 4);
    __hip_bfloat16* catA = (__hip_bfloat16*)alloc((size_t)N_PAD * SC * 2);
    __hip_bfloat16* catB = (__hip_bfloat16*)alloc((size_t)N_PAD * SC * 2);
    __hip_bfloat16* Wcat = (__hip_bfloat16*)alloc((size_t)3 * 96 * SC * 2);
    float* pooled = (float*)alloc((size_t)(N_GRAPHS * D + N_GRAPHS) * 4);
    float* cntg   = pooled + N_GRAPHS * D;

    hipMemsetAsync(cnt, 0, (size_t)N_NODES * 4, stream);
    hipMemsetAsync(pooled, 0, (size_t)(N_GRAPHS * D + N_GRAPHS) * 4, stream);

    const int NB = (N_NODES + 255) / 256;  // 196
    k_count<<<(N_EDGES + 255) / 256, 256, 0, stream>>>(dstI, cnt);
    k_scan1<<<NB, 256, 0, stream>>>(cnt, bsum);
    k_scan2<<<1, 256, 0, stream>>>(bsum, bpre, NB);
    k_scan3<<<NB, 256, 0, stream>>>(cnt, bpre, off, cursor);
    k_fill<<<(N_EDGES + 255) / 256, 256, 0, stream>>>(srcI, dstI, cursor, csr);
    k_prepw<<<(3 * 96 * SC + 255) / 256, 256, 0, stream>>>(W1l, W1r, W2l, W2r, W3l, W3r, Wcat);
    k_cvt<<<(N_PAD * 96 + 255) / 256, 256, 0, stream>>>(x, catA);

    const int AGG_BLOCKS  = N_NODES / 4;   // 12500 (4 waves/block, 1 node/wave)
    const int GEMM_BLOCKS = N_PAD / 64;    // 782

    unsigned int* catAu = (unsigned int*)catA;
    unsigned int* catBu = (unsigned int*)catB;

    // layer 1: agg(x) into catA cols 0..95; gemm catA -> catB h-region
    k_agg<<<AGG_BLOCKS, 256, 0, stream>>>(catAu, off, csr);
    k_gemm<<<GEMM_BLOCKS, 256, 0, stream>>>(catA, Wcat, b1, catB);
    // layer 2
    k_agg<<<AGG_BLOCKS, 256, 0, stream>>>(catBu, off, csr);
    k_gemm<<<GEMM_BLOCKS, 256, 0, stream>>>(catB, Wcat + 96 * SC, b2, catA);
    // layer 3
    k_agg<<<AGG_BLOCKS, 256, 0, stream>>>(catAu, off, csr);
    k_gemm<<<GEMM_BLOCKS, 256, 0, stream>>>(catA, Wcat + 2 * 96 * SC, b3, catB);

    k_pool<<<POOL_WAVES / 4, 256, 0, stream>>>(catBu, batch, pooled, cntg);
    k_mlp<<<1, 256, 0, stream>>>(pooled, cntg, Wf1, bf1, Wf2, bf2, (float*)d_out);
}

// Round 7
// 307.963 us; speedup vs baseline: 3.9128x; 1.0623x over previous
//
#include <hip/hip_runtime.h>
#include <hip/hip_bf16.h>

#define N_NODES 50000
#define N_PAD   50048   // padded to multiple of 64 rows
#define N_EDGES 800000
#define N_GRAPHS 64
#define D 90
#define SC  192   // cat row stride, bf16 elems: [agg(96) | h(96)]
#define SCD 96    // cat row stride in dwords

typedef __attribute__((ext_vector_type(8))) short bf16x8;
typedef __attribute__((ext_vector_type(4))) float f32x4;

__device__ __forceinline__ float bflo(unsigned int v) { return __uint_as_float(v << 16); }
__device__ __forceinline__ float bfhi(unsigned int v) { return __uint_as_float(v & 0xffff0000u); }
__device__ __forceinline__ unsigned short bf16bits(float f) {
    __hip_bfloat16 b = __float2bfloat16(f);
    return *(unsigned short*)&b;
}
__device__ __forceinline__ unsigned int pack2bf(float lo, float hi) {
    return (unsigned int)bf16bits(lo) | ((unsigned int)bf16bits(hi) << 16);
}

// ---------------- CSR build ----------------
__global__ void k_count(const int* __restrict__ dst, int* __restrict__ cnt) {
    int e = blockIdx.x * 256 + threadIdx.x;
    if (e < N_EDGES) atomicAdd(&cnt[dst[e]], 1);
}

__global__ void k_scan1(const int* __restrict__ cnt, int* __restrict__ bsum) {
    __shared__ int s[256];
    int t = threadIdx.x;
    int i = blockIdx.x * 256 + t;
    s[t] = (i < N_NODES) ? cnt[i] : 0;
    __syncthreads();
    for (int o = 128; o > 0; o >>= 1) { if (t < o) s[t] += s[t + o]; __syncthreads(); }
    if (t == 0) bsum[blockIdx.x] = s[0];
}

__global__ void k_scan2(const int* __restrict__ bsum, int* __restrict__ bpre, int nb) {
    __shared__ int s[256];
    int t = threadIdx.x;
    int v = (t < nb) ? bsum[t] : 0;
    s[t] = v; __syncthreads();
    for (int o = 1; o < 256; o <<= 1) {
        int x = (t >= o) ? s[t - o] : 0;
        __syncthreads();
        s[t] += x;
        __syncthreads();
    }
    bpre[t] = s[t] - v;  // exclusive
}

__global__ void k_scan3(const int* __restrict__ cnt, const int* __restrict__ bpre,
                        int* __restrict__ off, int* __restrict__ cursor) {
    __shared__ int s[256];
    int t = threadIdx.x;
    int i = blockIdx.x * 256 + t;
    int v = (i < N_NODES) ? cnt[i] : 0;
    s[t] = v; __syncthreads();
    for (int o = 1; o < 256; o <<= 1) {
        int x = (t >= o) ? s[t - o] : 0;
        __syncthreads();
        s[t] += x;
        __syncthreads();
    }
    int excl = s[t] - v + bpre[blockIdx.x];
    if (i < N_NODES) { off[i] = excl; cursor[i] = excl; }
    if (i == N_NODES - 1) off[N_NODES] = excl + v;
}

__global__ void k_fill(const int* __restrict__ src, const int* __restrict__ dst,
                       int* __restrict__ cursor, int* __restrict__ csr) {
    int e = blockIdx.x * 256 + threadIdx.x;
    if (e >= N_EDGES) return;
    int p = atomicAdd(&cursor[dst[e]], 1);
    csr[p] = src[e];
}

// ---------------- Wcat: [3 layers][96 j][192 k] bf16, row j = [Wl[j](pad96) | Wr[j](pad96)] ----------------
__global__ void k_prepw(const float* __restrict__ w1l, const float* __restrict__ w1r,
                        const float* __restrict__ w2l, const float* __restrict__ w2r,
                        const float* __restrict__ w3l, const float* __restrict__ w3r,
                        __hip_bfloat16* __restrict__ Wcat) {
    int idx = blockIdx.x * 256 + threadIdx.x;
    const int per = 96 * SC;
    if (idx >= 3 * per) return;
    int layer = idx / per, rem = idx - layer * per;
    int j = rem / SC, k = rem - j * SC;
    const float* wl = (layer == 0) ? w1l : (layer == 1) ? w2l : w3l;
    const float* wr = (layer == 0) ? w1r : (layer == 1) ? w2r : w3r;
    float v = 0.f;
    if (j < D) {
        if (k < 96) { if (k < D) v = wl[j * D + k]; }
        else        { int kk = k - 96; if (kk < D) v = wr[j * D + kk]; }
    }
    Wcat[idx] = __float2bfloat16(v);
}

// ---------------- x f32 [N][90] -> cat h-region (cols 96..191) bf16, pads zeroed ----------------
__global__ void k_cvt(const float* __restrict__ x, __hip_bfloat16* __restrict__ cat) {
    int idx = blockIdx.x * 256 + threadIdx.x;  // over N_PAD*96 (h-region elems)
    if (idx >= N_PAD * 96) return;
    int n = idx / 96, k = idx - n * 96;
    float v = (n < N_NODES && k < D) ? x[n * D + k] : 0.f;
    cat[n * SC + 96 + k] = __float2bfloat16(v);
}

// ---------------- mean aggregation: 1 wave per node, 16 lanes/edge, 4 edges/step, x2 unroll ----------------
__global__ void k_agg(unsigned int* __restrict__ cat,
                      const int* __restrict__ off, const int* __restrict__ csr) {
    int wid  = (blockIdx.x * 256 + threadIdx.x) >> 6;
    int lane = threadIdx.x & 63;
    if (wid >= N_NODES) return;
    int beg = off[wid], end = off[wid + 1];
    int eg = lane >> 4, sl = lane & 15;
    int col = 48 + 3 * sl;

    float a0 = 0.f, a1 = 0.f, a2 = 0.f, a3 = 0.f, a4 = 0.f, a5 = 0.f;
    int e = beg + eg;
    for (; e + 4 < end; e += 8) {
        int sA = csr[e], sB = csr[e + 4];
        const unsigned int* pA = &cat[sA * SCD + col];
        const unsigned int* pB = &cat[sB * SCD + col];
        unsigned int u0 = pA[0], u1 = pA[1], u2 = pA[2];
        unsigned int v0 = pB[0], v1 = pB[1], v2 = pB[2];
        a0 += bflo(u0) + bflo(v0); a1 += bfhi(u0) + bfhi(v0);
        a2 += bflo(u1) + bflo(v1); a3 += bfhi(u1) + bfhi(v1);
        a4 += bflo(u2) + bflo(v2); a5 += bfhi(u2) + bfhi(v2);
    }
    if (e < end) {
        const unsigned int* pA = &cat[csr[e] * SCD + col];
        unsigned int u0 = pA[0], u1 = pA[1], u2 = pA[2];
        a0 += bflo(u0); a1 += bfhi(u0);
        a2 += bflo(u1); a3 += bfhi(u1);
        a4 += bflo(u2); a5 += bfhi(u2);
    }

    // fold edge groups: lanes differing in bits 4,5 hold same sl
    #pragma unroll
    for (int m = 16; m <= 32; m <<= 1) {
        a0 += __shfl_xor(a0, m);
        a1 += __shfl_xor(a1, m);
        a2 += __shfl_xor(a2, m);
        a3 += __shfl_xor(a3, m);
        a4 += __shfl_xor(a4, m);
        a5 += __shfl_xor(a5, m);
    }

    if (eg == 0) {
        float inv = 1.0f / fmaxf((float)(end - beg), 1.0f);
        bool pad = (sl == 15);  // elems 90..95
        unsigned int* q = &cat[wid * SCD + 3 * sl];
        q[0] = pad ? 0u : pack2bf(a0 * inv, a1 * inv);
        q[1] = pad ? 0u : pack2bf(a2 * inv, a3 * inv);
        q[2] = pad ? 0u : pack2bf(a4 * inv, a5 * inv);
    }
}

// ---------------- MFMA dual-GEMM + bias + ReLU ----------------
__global__ __launch_bounds__(256) void k_gemm(
    const __hip_bfloat16* __restrict__ Acat,  // [N_PAD][192]
    const __hip_bfloat16* __restrict__ Wcat,  // [96][192]
    const float* __restrict__ bias,           // [90]
    __hip_bfloat16* __restrict__ Hout)        // [N_PAD][192], writes cols 96..191
{
    __shared__ float biasPad[96];
    int tid = threadIdx.x;
    if (tid < 96) biasPad[tid] = (tid < D) ? bias[tid] : 0.f;
    __syncthreads();

    int w = tid >> 6, lane = tid & 63;
    int r0 = blockIdx.x * 64 + w * 16;
    int mrow = lane & 15, kg = lane >> 4;   // A row within tile; k-group 0..3

    const short* A = (const short*)Acat;
    const short* W = (const short*)Wcat;

    f32x4 acc[6];
    #pragma unroll
    for (int t = 0; t < 6; ++t) {
        float b = biasPad[t * 16 + mrow];   // C col = lane&15
        acc[t] = (f32x4){b, b, b, b};
    }

    #pragma unroll
    for (int ks = 0; ks < 6; ++ks) {
        bf16x8 a = *(const bf16x8*)&A[(r0 + mrow) * SC + ks * 32 + kg * 8];
        #pragma unroll
        for (int t = 0; t < 6; ++t) {
            bf16x8 bfr = *(const bf16x8*)&W[(t * 16 + mrow) * SC + ks * 32 + kg * 8];
            acc[t] = __builtin_amdgcn_mfma_f32_16x16x32_bf16(a, bfr, acc[t], 0, 0, 0);
        }
    }

    // C/D layout (m89): col = lane&15, row = (lane>>4)*4 + v
    int orow = r0 + kg * 4;
    #pragma unroll
    for (int t = 0; t < 6; ++t) {
        int j = t * 16 + mrow;
        #pragma unroll
        for (int v = 0; v < 4; ++v) {
            float val = (j < D) ? fmaxf(acc[t][v], 0.f) : 0.f;
            Hout[(orow + v) * SC + 96 + j] = __float2bfloat16(val);
        }
    }
}

// ---------------- graph mean pool: segmented reduction (batch sorted), high-parallelism ----------------
#define POOL_WAVES 4096
__global__ void k_pool(const unsigned int* __restrict__ cat, const int* __restrict__ batch,
                       float* __restrict__ pooled, float* __restrict__ cntg) {
    int wid  = (blockIdx.x * blockDim.x + threadIdx.x) >> 6;
    int lane = threadIdx.x & 63;
    const int per = (N_NODES + POOL_WAVES - 1) / POOL_WAVES;  // 13
    int beg = wid * per;
    int end = beg + per; if (end > N_NODES) end = N_NODES;
    if (beg >= end) return;
    int cur = batch[beg];
    float a0 = 0.f, a1 = 0.f, c = 0.f;
    for (int n = beg; n < end; ++n) {
        int g = batch[n];
        if (g != cur) {
            if (lane < 45) {
                atomicAdd(&pooled[cur * D + 2 * lane], a0);
                atomicAdd(&pooled[cur * D + 2 * lane + 1], a1);
            }
            if (lane == 0) atomicAdd(&cntg[cur], c);
            a0 = a1 = c = 0.f;
            cur = g;
        }
        if (lane < 45) {
            unsigned int v = cat[n * SCD + 48 + lane];
            a0 += bflo(v);
            a1 += bfhi(v);
        }
        c += 1.f;
    }
    if (lane < 45) {
        atomicAdd(&pooled[cur * D + 2 * lane], a0);
        atomicAdd(&pooled[cur * D + 2 * lane + 1], a1);
    }
    if (lane == 0) atomicAdd(&cntg[cur], c);
}

// ---------------- final MLP (single block) ----------------
__global__ void k_mlp(const float* __restrict__ pooled, const float* __restrict__ cntg,
                      const float* __restrict__ Wf1, const float* __restrict__ bf1,
                      const float* __restrict__ Wf2, const float* __restrict__ bf2,
                      float* __restrict__ outp) {
    __shared__ float P[N_GRAPHS][92];
    __shared__ float H4[N_GRAPHS][32];
    int tid = threadIdx.x;
    for (int idx = tid; idx < N_GRAPHS * D; idx += 256) {
        int g = idx / D, d = idx - g * D;
        P[g][d] = pooled[idx] / fmaxf(cntg[g], 1.0f);
    }
    __syncthreads();
    for (int idx = tid; idx < N_GRAPHS * 32; idx += 256) {
        int g = idx >> 5, c = idx & 31;
        float acc = bf1[c];
        for (int d = 0; d < D; ++d) acc += P[g][d] * Wf1[c * D + d];
        H4[g][c] = fmaxf(acc, 0.f);
    }
    __syncthreads();
    if (tid < N_GRAPHS) {
        float acc = bf2[0];
        #pragma unroll
        for (int c = 0; c < 32; ++c) acc += H4[tid][c] * Wf2[c];
        outp[tid] = acc;
    }
}

extern "C" void kernel_launch(void* const* d_in, const int* in_sizes, int n_in,
                              void* d_out, int out_size, void* d_ws, size_t ws_size,
                              hipStream_t stream) {
    const float* x    = (const float*)d_in[0];
    const int*   ei   = (const int*)d_in[1];
    const int*   batch= (const int*)d_in[2];
    const float* W1l  = (const float*)d_in[3];
    const float* b1   = (const float*)d_in[4];
    const float* W1r  = (const float*)d_in[5];
    const float* W2l  = (const float*)d_in[6];
    const float* b2   = (const float*)d_in[7];
    const float* W2r  = (const float*)d_in[8];
    const float* W3l  = (const float*)d_in[9];
    const float* b3   = (const float*)d_in[10];
    const float* W3r  = (const float*)d_in[11];
    const float* Wf1  = (const float*)d_in[12];
    const float* bf1  = (const float*)d_in[13];
    const float* Wf2  = (const float*)d_in[14];
    const float* bf2  = (const float*)d_in[15];
    const int* srcI = ei;
    const int* dstI = ei + N_EDGES;

    char* base = (char*)d_ws;
    size_t o = 0;
    auto alloc = [&](size_t bytes) -> void* {
        void* p = base + o;
        o = (o + bytes + 255) & ~(size_t)255;
        return p;
    };
    int*   cnt    = (int*)alloc((size_t)N_NODES * 4);
    int*   cursor = (int*)alloc((size_t)N_NODES * 4);
    int*   off    = (int*)alloc((size_t)(N_NODES + 1) * 4);
    int*   bsum   = (int*)alloc(256 * 4);
    int*   bpre   = (int*)alloc(256 * 4);
    int*   csr    = (int*)alloc((size_t)N_EDGES * 4);
    __hip_bfloat16* catA = (__hip_bfloat16*)alloc((size_t)N_PAD * SC * 2);
    __hip_bfloat16* catB = (__hip_bfloat16*)alloc((size_t)N_PAD * SC * 2);
    __hip_bfloat16* Wcat = (__hip_bfloat16*)alloc((size_t)3 * 96 * SC * 2);
    float* pooled = (float*)alloc((size_t)(N_GRAPHS * D + N_GRAPHS) * 4);
    float* cntg   = pooled + N_GRAPHS * D;

    hipMemsetAsync(cnt, 0, (size_t)N_NODES * 4, stream);
    hipMemsetAsync(pooled, 0, (size_t)(N_GRAPHS * D + N_GRAPHS) * 4, stream);

    const int NB = (N_NODES + 255) / 256;  // 196
    k_count<<<(N_EDGES + 255) / 256, 256, 0, stream>>>(dstI, cnt);
    k_scan1<<<NB, 256, 0, stream>>>(cnt, bsum);
    k_scan2<<<1, 256, 0, stream>>>(bsum, bpre, NB);
    k_scan3<<<NB, 256, 0, stream>>>(cnt, bpre, off, cursor);
    k_fill<<<(N_EDGES + 255) / 256, 256, 0, stream>>>(srcI, dstI, cursor, csr);
    k_prepw<<<(3 * 96 * SC + 255) / 256, 256, 0, stream>>>(W1l, W1r, W2l, W2r, W3l, W3r, Wcat);
    k_cvt<<<(N_PAD * 96 + 255) / 256, 256, 0, stream>>>(x, catA);

    const int AGG_BLOCKS  = N_NODES / 4;   // 12500 (4 waves/block, 1 node/wave)
    const int GEMM_BLOCKS = N_PAD / 64;    // 782

    unsigned int* catAu = (unsigned int*)catA;
    unsigned int* catBu = (unsigned int*)catB;

    // layer 1: agg(x) into catA cols 0..95; gemm catA -> catB h-region
    k_agg<<<AGG_BLOCKS, 256, 0, stream>>>(catAu, off, csr);
    k_gemm<<<GEMM_BLOCKS, 256, 0, stream>>>(catA, Wcat, b1, catB);
    // layer 2
    k_agg<<<AGG_BLOCKS, 256, 0, stream>>>(catBu, off, csr);
    k_gemm<<<GEMM_BLOCKS, 256, 0, stream>>>(catB, Wcat + 96 * SC, b2, catA);
    // layer 3
    k_agg<<<AGG_BLOCKS, 256, 0, stream>>>(catAu, off, csr);
    k_gemm<<<GEMM_BLOCKS, 256, 0, stream>>>(catA, Wcat + 2 * 96 * SC, b3, catB);

    k_pool<<<POOL_WAVES / 4, 256, 0, stream>>>(catBu, batch, pooled, cntg);
    k_mlp<<<1, 256, 0, stream>>>(pooled, cntg, Wf1, bf1, Wf2, bf2, (float*)d_out);
}

// Round 8
// 252.189 us; speedup vs baseline: 4.7781x; 1.2212x over previous
//
#include <hip/hip_runtime.h>
#include <hip/hip_bf16.h>

#define N_NODES 50000
#define N_PAD   50048   // padded to multiple of 64 rows
#define N_EDGES 800000
#define N_GRAPHS 64
#define D 90
#define SC  192   // cat row stride, bf16 elems: [agg(96) | h(96)]
#define SCD 96    // cat row stride in dwords

#define NBUCKETS 196    // ceil(N_NODES/256): 256 nodes per bucket
#define BSHIFT 8
#define BIN_EPB 4096    // edges per block in hist/bin

typedef __attribute__((ext_vector_type(8))) short bf16x8;
typedef __attribute__((ext_vector_type(4))) float f32x4;

__device__ __forceinline__ float bflo(unsigned int v) { return __uint_as_float(v << 16); }
__device__ __forceinline__ float bfhi(unsigned int v) { return __uint_as_float(v & 0xffff0000u); }
__device__ __forceinline__ unsigned short bf16bits(float f) {
    __hip_bfloat16 b = __float2bfloat16(f);
    return *(unsigned short*)&b;
}
__device__ __forceinline__ unsigned int pack2bf(float lo, float hi) {
    return (unsigned int)bf16bits(lo) | ((unsigned int)bf16bits(hi) << 16);
}

// ---------------- CSR build: bucket-local, write-coalesced ----------------
// bucket b = nodes [256b, 256b+256); bucket base in CSR = off[256b] = bbase[b].

__global__ void k_hist(const int* __restrict__ dst, int* __restrict__ bcnt) {
    __shared__ int h[NBUCKETS];
    int t = threadIdx.x;
    for (int i = t; i < NBUCKETS; i += 256) h[i] = 0;
    __syncthreads();
    int base = blockIdx.x * BIN_EPB;
    int lim = base + BIN_EPB; if (lim > N_EDGES) lim = N_EDGES;
    for (int e = base + t; e < lim; e += 256)
        atomicAdd(&h[dst[e] >> BSHIFT], 1);
    __syncthreads();
    for (int i = t; i < NBUCKETS; i += 256) {
        int c = h[i];
        if (c) atomicAdd(&bcnt[i], c);
    }
}

__global__ void k_bscan(const int* __restrict__ bcnt, int* __restrict__ bbase,
                        int* __restrict__ bcursor) {
    __shared__ int s[256];
    int t = threadIdx.x;
    int v = (t < NBUCKETS) ? bcnt[t] : 0;
    s[t] = v; __syncthreads();
    for (int o = 1; o < 256; o <<= 1) {
        int x = (t >= o) ? s[t - o] : 0;
        __syncthreads();
        s[t] += x;
        __syncthreads();
    }
    int excl = s[t] - v;
    if (t < NBUCKETS) { bbase[t] = excl; bcursor[t] = excl; }
    if (t == 255) bbase[NBUCKETS] = s[255];   // total = N_EDGES
}

// scatter packed entries (src | (dst&255)<<16) into bucket-partitioned ebuf.
// per-block chunk allocation -> each block-bucket region has a single writer.
__global__ __launch_bounds__(256) void k_bin(const int* __restrict__ src,
                                             const int* __restrict__ dst,
                                             int* __restrict__ bcursor,
                                             unsigned int* __restrict__ ebuf) {
    __shared__ int h[NBUCKETS];
    __shared__ int gb[NBUCKETS];
    int t = threadIdx.x;
    for (int i = t; i < NBUCKETS; i += 256) h[i] = 0;
    __syncthreads();
    int base = blockIdx.x * BIN_EPB;
    int sv[16], dv[16], rv[16];
    #pragma unroll
    for (int i = 0; i < 16; ++i) {
        int e = base + i * 256 + t;
        if (e < N_EDGES) {
            sv[i] = src[e];
            dv[i] = dst[e];
            rv[i] = atomicAdd(&h[dv[i] >> BSHIFT], 1);
        }
    }
    __syncthreads();
    for (int i = t; i < NBUCKETS; i += 256)
        gb[i] = h[i] ? atomicAdd(&bcursor[i], h[i]) : 0;
    __syncthreads();
    #pragma unroll
    for (int i = 0; i < 16; ++i) {
        int e = base + i * 256 + t;
        if (e < N_EDGES) {
            int b = dv[i] >> BSHIFT;
            ebuf[gb[b] + rv[i]] = (unsigned int)sv[i] | ((unsigned int)(dv[i] & 255) << 16);
        }
    }
}

// one block per bucket: per-node count + scan in LDS, write off[] and csr densely.
__global__ __launch_bounds__(256) void k_fill2(const unsigned int* __restrict__ ebuf,
                                               const int* __restrict__ bbase,
                                               int* __restrict__ off,
                                               int* __restrict__ csr) {
    __shared__ int lcnt[256];
    __shared__ int excl[256];
    int t = threadIdx.x;
    int n0 = blockIdx.x << BSHIFT;
    int ebeg = bbase[blockIdx.x], eend = bbase[blockIdx.x + 1];
    lcnt[t] = 0;
    __syncthreads();
    for (int e = ebeg + t; e < eend; e += 256)
        atomicAdd(&lcnt[ebuf[e] >> 16], 1);
    __syncthreads();
    int v = lcnt[t];
    excl[t] = v; __syncthreads();
    for (int o = 1; o < 256; o <<= 1) {
        int x = (t >= o) ? excl[t - o] : 0;
        __syncthreads();
        excl[t] += x;
        __syncthreads();
    }
    excl[t] -= v;           // exclusive prefix within bucket
    int n = n0 + t;
    if (n <= N_NODES) off[n] = ebeg + excl[t];
    lcnt[t] = 0;
    __syncthreads();
    for (int e = ebeg + t; e < eend; e += 256) {
        unsigned int u = ebuf[e];
        int li = u >> 16;
        int r = atomicAdd(&lcnt[li], 1);
        csr[ebeg + excl[li] + r] = (int)(u & 0xFFFFu);
    }
}

// ---------------- Wcat: [3 layers][96 j][192 k] bf16, row j = [Wl[j](pad96) | Wr[j](pad96)] ----------------
__global__ void k_prepw(const float* __restrict__ w1l, const float* __restrict__ w1r,
                        const float* __restrict__ w2l, const float* __restrict__ w2r,
                        const float* __restrict__ w3l, const float* __restrict__ w3r,
                        __hip_bfloat16* __restrict__ Wcat) {
    int idx = blockIdx.x * 256 + threadIdx.x;
    const int per = 96 * SC;
    if (idx >= 3 * per) return;
    int layer = idx / per, rem = idx - layer * per;
    int j = rem / SC, k = rem - j * SC;
    const float* wl = (layer == 0) ? w1l : (layer == 1) ? w2l : w3l;
    const float* wr = (layer == 0) ? w1r : (layer == 1) ? w2r : w3r;
    float v = 0.f;
    if (j < D) {
        if (k < 96) { if (k < D) v = wl[j * D + k]; }
        else        { int kk = k - 96; if (kk < D) v = wr[j * D + kk]; }
    }
    Wcat[idx] = __float2bfloat16(v);
}

// ---------------- x f32 [N][90] -> cat h-region (cols 96..191) bf16, pads zeroed ----------------
__global__ void k_cvt(const float* __restrict__ x, __hip_bfloat16* __restrict__ cat) {
    int idx = blockIdx.x * 256 + threadIdx.x;  // over N_PAD*96 (h-region elems)
    if (idx >= N_PAD * 96) return;
    int n = idx / 96, k = idx - n * 96;
    float v = (n < N_NODES && k < D) ? x[n * D + k] : 0.f;
    cat[n * SC + 96 + k] = __float2bfloat16(v);
}

// ---------------- mean aggregation: 1 wave per node, 16 lanes/edge, 4 edges/step, x2 unroll ----------------
__global__ void k_agg(unsigned int* __restrict__ cat,
                      const int* __restrict__ off, const int* __restrict__ csr) {
    int wid  = (blockIdx.x * 256 + threadIdx.x) >> 6;
    int lane = threadIdx.x & 63;
    if (wid >= N_NODES) return;
    int beg = off[wid], end = off[wid + 1];
    int eg = lane >> 4, sl = lane & 15;
    int col = 48 + 3 * sl;

    float a0 = 0.f, a1 = 0.f, a2 = 0.f, a3 = 0.f, a4 = 0.f, a5 = 0.f;
    int e = beg + eg;
    for (; e + 4 < end; e += 8) {
        int sA = csr[e], sB = csr[e + 4];
        const unsigned int* pA = &cat[sA * SCD + col];
        const unsigned int* pB = &cat[sB * SCD + col];
        unsigned int u0 = pA[0], u1 = pA[1], u2 = pA[2];
        unsigned int v0 = pB[0], v1 = pB[1], v2 = pB[2];
        a0 += bflo(u0) + bflo(v0); a1 += bfhi(u0) + bfhi(v0);
        a2 += bflo(u1) + bflo(v1); a3 += bfhi(u1) + bfhi(v1);
        a4 += bflo(u2) + bflo(v2); a5 += bfhi(u2) + bfhi(v2);
    }
    if (e < end) {
        const unsigned int* pA = &cat[csr[e] * SCD + col];
        unsigned int u0 = pA[0], u1 = pA[1], u2 = pA[2];
        a0 += bflo(u0); a1 += bfhi(u0);
        a2 += bflo(u1); a3 += bfhi(u1);
        a4 += bflo(u2); a5 += bfhi(u2);
    }

    // fold edge groups: lanes differing in bits 4,5 hold same sl
    #pragma unroll
    for (int m = 16; m <= 32; m <<= 1) {
        a0 += __shfl_xor(a0, m);
        a1 += __shfl_xor(a1, m);
        a2 += __shfl_xor(a2, m);
        a3 += __shfl_xor(a3, m);
        a4 += __shfl_xor(a4, m);
        a5 += __shfl_xor(a5, m);
    }

    if (eg == 0) {
        float inv = 1.0f / fmaxf((float)(end - beg), 1.0f);
        bool pad = (sl == 15);  // elems 90..95
        unsigned int* q = &cat[wid * SCD + 3 * sl];
        q[0] = pad ? 0u : pack2bf(a0 * inv, a1 * inv);
        q[1] = pad ? 0u : pack2bf(a2 * inv, a3 * inv);
        q[2] = pad ? 0u : pack2bf(a4 * inv, a5 * inv);
    }
}

// ---------------- MFMA dual-GEMM + bias + ReLU ----------------
__global__ __launch_bounds__(256) void k_gemm(
    const __hip_bfloat16* __restrict__ Acat,  // [N_PAD][192]
    const __hip_bfloat16* __restrict__ Wcat,  // [96][192]
    const float* __restrict__ bias,           // [90]
    __hip_bfloat16* __restrict__ Hout)        // [N_PAD][192], writes cols 96..191
{
    __shared__ float biasPad[96];
    int tid = threadIdx.x;
    if (tid < 96) biasPad[tid] = (tid < D) ? bias[tid] : 0.f;
    __syncthreads();

    int w = tid >> 6, lane = tid & 63;
    int r0 = blockIdx.x * 64 + w * 16;
    int mrow = lane & 15, kg = lane >> 4;   // A row within tile; k-group 0..3

    const short* A = (const short*)Acat;
    const short* W = (const short*)Wcat;

    f32x4 acc[6];
    #pragma unroll
    for (int t = 0; t < 6; ++t) {
        float b = biasPad[t * 16 + mrow];   // C col = lane&15
        acc[t] = (f32x4){b, b, b, b};
    }

    #pragma unroll
    for (int ks = 0; ks < 6; ++ks) {
        bf16x8 a = *(const bf16x8*)&A[(r0 + mrow) * SC + ks * 32 + kg * 8];
        #pragma unroll
        for (int t = 0; t < 6; ++t) {
            bf16x8 bfr = *(const bf16x8*)&W[(t * 16 + mrow) * SC + ks * 32 + kg * 8];
            acc[t] = __builtin_amdgcn_mfma_f32_16x16x32_bf16(a, bfr, acc[t], 0, 0, 0);
        }
    }

    // C/D layout (m89): col = lane&15, row = (lane>>4)*4 + v
    int orow = r0 + kg * 4;
    #pragma unroll
    for (int t = 0; t < 6; ++t) {
        int j = t * 16 + mrow;
        #pragma unroll
        for (int v = 0; v < 4; ++v) {
            float val = (j < D) ? fmaxf(acc[t][v], 0.f) : 0.f;
            Hout[(orow + v) * SC + 96 + j] = __float2bfloat16(val);
        }
    }
}

// ---------------- graph mean pool: segmented reduction (batch sorted), high-parallelism ----------------
#define POOL_WAVES 4096
__global__ void k_pool(const unsigned int* __restrict__ cat, const int* __restrict__ batch,
                       float* __restrict__ pooled, float* __restrict__ cntg) {
    int wid  = (blockIdx.x * blockDim.x + threadIdx.x) >> 6;
    int lane = threadIdx.x & 63;
    const int per = (N_NODES + POOL_WAVES - 1) / POOL_WAVES;  // 13
    int beg = wid * per;
    int end = beg + per; if (end > N_NODES) end = N_NODES;
    if (beg >= end) return;
    int cur = batch[beg];
    float a0 = 0.f, a1 = 0.f, c = 0.f;
    for (int n = beg; n < end; ++n) {
        int g = batch[n];
        if (g != cur) {
            if (lane < 45) {
                atomicAdd(&pooled[cur * D + 2 * lane], a0);
                atomicAdd(&pooled[cur * D + 2 * lane + 1], a1);
            }
            if (lane == 0) atomicAdd(&cntg[cur], c);
            a0 = a1 = c = 0.f;
            cur = g;
        }
        if (lane < 45) {
            unsigned int v = cat[n * SCD + 48 + lane];
            a0 += bflo(v);
            a1 += bfhi(v);
        }
        c += 1.f;
    }
    if (lane < 45) {
        atomicAdd(&pooled[cur * D + 2 * lane], a0);
        atomicAdd(&pooled[cur * D + 2 * lane + 1], a1);
    }
    if (lane == 0) atomicAdd(&cntg[cur], c);
}

// ---------------- final MLP (single block) ----------------
__global__ void k_mlp(const float* __restrict__ pooled, const float* __restrict__ cntg,
                      const float* __restrict__ Wf1, const float* __restrict__ bf1,
                      const float* __restrict__ Wf2, const float* __restrict__ bf2,
                      float* __restrict__ outp) {
    __shared__ float P[N_GRAPHS][92];
    __shared__ float H4[N_GRAPHS][32];
    int tid = threadIdx.x;
    for (int idx = tid; idx < N_GRAPHS * D; idx += 256) {
        int g = idx / D, d = idx - g * D;
        P[g][d] = pooled[idx] / fmaxf(cntg[g], 1.0f);
    }
    __syncthreads();
    for (int idx = tid; idx < N_GRAPHS * 32; idx += 256) {
        int g = idx >> 5, c = idx & 31;
        float acc = bf1[c];
        for (int d = 0; d < D; ++d) acc += P[g][d] * Wf1[c * D + d];
        H4[g][c] = fmaxf(acc, 0.f);
    }
    __syncthreads();
    if (tid < N_GRAPHS) {
        float acc = bf2[0];
        #pragma unroll
        for (int c = 0; c < 32; ++c) acc += H4[tid][c] * Wf2[c];
        outp[tid] = acc;
    }
}

extern "C" void kernel_launch(void* const* d_in, const int* in_sizes, int n_in,
                              void* d_out, int out_size, void* d_ws, size_t ws_size,
                              hipStream_t stream) {
    const float* x    = (const float*)d_in[0];
    const int*   ei   = (const int*)d_in[1];
    const int*   batch= (const int*)d_in[2];
    const float* W1l  = (const float*)d_in[3];
    const float* b1   = (const float*)d_in[4];
    const float* W1r  = (const float*)d_in[5];
    const float* W2l  = (const float*)d_in[6];
    const float* b2   = (const float*)d_in[7];
    const float* W2r  = (const float*)d_in[8];
    const float* W3l  = (const float*)d_in[9];
    const float* b3   = (const float*)d_in[10];
    const float* W3r  = (const float*)d_in[11];
    const float* Wf1  = (const float*)d_in[12];
    const float* bf1  = (const float*)d_in[13];
    const float* Wf2  = (const float*)d_in[14];
    const float* bf2  = (const float*)d_in[15];
    const int* srcI = ei;
    const int* dstI = ei + N_EDGES;

    char* base = (char*)d_ws;
    size_t o = 0;
    auto alloc = [&](size_t bytes) -> void* {
        void* p = base + o;
        o = (o + bytes + 255) & ~(size_t)255;
        return p;
    };
    int*   bcnt    = (int*)alloc((size_t)NBUCKETS * 4);
    int*   bbase   = (int*)alloc((size_t)(NBUCKETS + 1) * 4);
    int*   bcursor = (int*)alloc((size_t)NBUCKETS * 4);
    int*   off     = (int*)alloc((size_t)(N_NODES + 1) * 4);
    unsigned int* ebuf = (unsigned int*)alloc((size_t)N_EDGES * 4);
    int*   csr     = (int*)alloc((size_t)N_EDGES * 4);
    __hip_bfloat16* catA = (__hip_bfloat16*)alloc((size_t)N_PAD * SC * 2);
    __hip_bfloat16* catB = (__hip_bfloat16*)alloc((size_t)N_PAD * SC * 2);
    __hip_bfloat16* Wcat = (__hip_bfloat16*)alloc((size_t)3 * 96 * SC * 2);
    float* pooled = (float*)alloc((size_t)(N_GRAPHS * D + N_GRAPHS) * 4);
    float* cntg   = pooled + N_GRAPHS * D;

    hipMemsetAsync(bcnt, 0, (size_t)NBUCKETS * 4, stream);
    hipMemsetAsync(pooled, 0, (size_t)(N_GRAPHS * D + N_GRAPHS) * 4, stream);

    const int EB = (N_EDGES + BIN_EPB - 1) / BIN_EPB;  // 196
    k_hist<<<EB, 256, 0, stream>>>(dstI, bcnt);
    k_bscan<<<1, 256, 0, stream>>>(bcnt, bbase, bcursor);
    k_bin<<<EB, 256, 0, stream>>>(srcI, dstI, bcursor, ebuf);
    k_fill2<<<NBUCKETS, 256, 0, stream>>>(ebuf, bbase, off, csr);
    k_prepw<<<(3 * 96 * SC + 255) / 256, 256, 0, stream>>>(W1l, W1r, W2l, W2r, W3l, W3r, Wcat);
    k_cvt<<<(N_PAD * 96 + 255) / 256, 256, 0, stream>>>(x, catA);

    const int AGG_BLOCKS  = N_NODES / 4;   // 12500 (4 waves/block, 1 node/wave)
    const int GEMM_BLOCKS = N_PAD / 64;    // 782

    unsigned int* catAu = (unsigned int*)catA;
    unsigned int* catBu = (unsigned int*)catB;

    // layer 1: agg(x) into catA cols 0..95; gemm catA -> catB h-region
    k_agg<<<AGG_BLOCKS, 256, 0, stream>>>(catAu, off, csr);
    k_gemm<<<GEMM_BLOCKS, 256, 0, stream>>>(catA, Wcat, b1, catB);
    // layer 2
    k_agg<<<AGG_BLOCKS, 256, 0, stream>>>(catBu, off, csr);
    k_gemm<<<GEMM_BLOCKS, 256, 0, stream>>>(catB, Wcat + 96 * SC, b2, catA);
    // layer 3
    k_agg<<<AGG_BLOCKS, 256, 0, stream>>>(catAu, off, csr);
    k_gemm<<<GEMM_BLOCKS, 256, 0, stream>>>(catA, Wcat + 2 * 96 * SC, b3, catB);

    k_pool<<<POOL_WAVES / 4, 256, 0, stream>>>(catBu, batch, pooled, cntg);
    k_mlp<<<1, 256, 0, stream>>>(pooled, cntg, Wf1, bf1, Wf2, bf2, (float*)d_out);
}

// Round 9
// 249.701 us; speedup vs baseline: 4.8258x; 1.0100x over previous
//
#include <hip/hip_runtime.h>
#include <hip/hip_bf16.h>

#define N_NODES 50000
#define N_PAD   50048   // padded to multiple of 64 rows
#define N_EDGES 800000
#define N_GRAPHS 64
#define D 90
#define SC  192   // cat row stride, bf16 elems: [agg(96) | h(96)]
#define SCD 96    // cat row stride in dwords

#define NBUCKETS 196    // ceil(N_NODES/256): 256 nodes per bucket
#define BSHIFT 8
#define BIN_EPB 4096    // edges per block in hist/bin

typedef __attribute__((ext_vector_type(8))) short bf16x8;
typedef __attribute__((ext_vector_type(4))) float f32x4;

__device__ __forceinline__ float bflo(unsigned int v) { return __uint_as_float(v << 16); }
__device__ __forceinline__ float bfhi(unsigned int v) { return __uint_as_float(v & 0xffff0000u); }
__device__ __forceinline__ unsigned short bf16bits(float f) {
    __hip_bfloat16 b = __float2bfloat16(f);
    return *(unsigned short*)&b;
}
__device__ __forceinline__ unsigned int pack2bf(float lo, float hi) {
    return (unsigned int)bf16bits(lo) | ((unsigned int)bf16bits(hi) << 16);
}

// ---------------- graph-head zero-init (replaces hipMemsetAsync: ~40us each in-graph) ----------------
__global__ void k_init(int* __restrict__ bcnt, float* __restrict__ pooled) {
    int t = blockIdx.x * 256 + threadIdx.x;
    if (t < NBUCKETS) bcnt[t] = 0;
    if (t < N_GRAPHS * D + N_GRAPHS) pooled[t] = 0.f;
}

// ---------------- CSR build: bucket-local, write-coalesced ----------------
// bucket b = nodes [256b, 256b+256); bucket base in CSR = off[256b] = bbase[b].

__global__ void k_hist(const int* __restrict__ dst, int* __restrict__ bcnt) {
    __shared__ int h[NBUCKETS];
    int t = threadIdx.x;
    for (int i = t; i < NBUCKETS; i += 256) h[i] = 0;
    __syncthreads();
    int base = blockIdx.x * BIN_EPB;
    int lim = base + BIN_EPB; if (lim > N_EDGES) lim = N_EDGES;
    for (int e = base + t; e < lim; e += 256)
        atomicAdd(&h[dst[e] >> BSHIFT], 1);
    __syncthreads();
    for (int i = t; i < NBUCKETS; i += 256) {
        int c = h[i];
        if (c) atomicAdd(&bcnt[i], c);
    }
}

__global__ void k_bscan(const int* __restrict__ bcnt, int* __restrict__ bbase,
                        int* __restrict__ bcursor) {
    __shared__ int s[256];
    int t = threadIdx.x;
    int v = (t < NBUCKETS) ? bcnt[t] : 0;
    s[t] = v; __syncthreads();
    for (int o = 1; o < 256; o <<= 1) {
        int x = (t >= o) ? s[t - o] : 0;
        __syncthreads();
        s[t] += x;
        __syncthreads();
    }
    int excl = s[t] - v;
    if (t < NBUCKETS) { bbase[t] = excl; bcursor[t] = excl; }
    if (t == 255) bbase[NBUCKETS] = s[255];   // total = N_EDGES
}

// scatter packed entries (src | (dst&255)<<16) into bucket-partitioned ebuf.
// per-block chunk allocation -> each block-bucket region has a single writer.
__global__ __launch_bounds__(256) void k_bin(const int* __restrict__ src,
                                             const int* __restrict__ dst,
                                             int* __restrict__ bcursor,
                                             unsigned int* __restrict__ ebuf) {
    __shared__ int h[NBUCKETS];
    __shared__ int gb[NBUCKETS];
    int t = threadIdx.x;
    for (int i = t; i < NBUCKETS; i += 256) h[i] = 0;
    __syncthreads();
    int base = blockIdx.x * BIN_EPB;
    int sv[16], dv[16], rv[16];
    #pragma unroll
    for (int i = 0; i < 16; ++i) {
        int e = base + i * 256 + t;
        if (e < N_EDGES) {
            sv[i] = src[e];
            dv[i] = dst[e];
            rv[i] = atomicAdd(&h[dv[i] >> BSHIFT], 1);
        }
    }
    __syncthreads();
    for (int i = t; i < NBUCKETS; i += 256)
        gb[i] = h[i] ? atomicAdd(&bcursor[i], h[i]) : 0;
    __syncthreads();
    #pragma unroll
    for (int i = 0; i < 16; ++i) {
        int e = base + i * 256 + t;
        if (e < N_EDGES) {
            int b = dv[i] >> BSHIFT;
            ebuf[gb[b] + rv[i]] = (unsigned int)sv[i] | ((unsigned int)(dv[i] & 255) << 16);
        }
    }
}

// one block per bucket: per-node count + scan in LDS, write off[] and csr densely.
__global__ __launch_bounds__(256) void k_fill2(const unsigned int* __restrict__ ebuf,
                                               const int* __restrict__ bbase,
                                               int* __restrict__ off,
                                               int* __restrict__ csr) {
    __shared__ int lcnt[256];
    __shared__ int excl[256];
    int t = threadIdx.x;
    int n0 = blockIdx.x << BSHIFT;
    int ebeg = bbase[blockIdx.x], eend = bbase[blockIdx.x + 1];
    lcnt[t] = 0;
    __syncthreads();
    for (int e = ebeg + t; e < eend; e += 256)
        atomicAdd(&lcnt[ebuf[e] >> 16], 1);
    __syncthreads();
    int v = lcnt[t];
    excl[t] = v; __syncthreads();
    for (int o = 1; o < 256; o <<= 1) {
        int x = (t >= o) ? excl[t - o] : 0;
        __syncthreads();
        excl[t] += x;
        __syncthreads();
    }
    excl[t] -= v;           // exclusive prefix within bucket
    int n = n0 + t;
    if (n <= N_NODES) off[n] = ebeg + excl[t];
    lcnt[t] = 0;
    __syncthreads();
    for (int e = ebeg + t; e < eend; e += 256) {
        unsigned int u = ebuf[e];
        int li = u >> 16;
        int r = atomicAdd(&lcnt[li], 1);
        csr[ebeg + excl[li] + r] = (int)(u & 0xFFFFu);
    }
}

// ---------------- Wcat: [3 layers][96 j][192 k] bf16, row j = [Wl[j](pad96) | Wr[j](pad96)] ----------------
__global__ void k_prepw(const float* __restrict__ w1l, const float* __restrict__ w1r,
                        const float* __restrict__ w2l, const float* __restrict__ w2r,
                        const float* __restrict__ w3l, const float* __restrict__ w3r,
                        __hip_bfloat16* __restrict__ Wcat) {
    int idx = blockIdx.x * 256 + threadIdx.x;
    const int per = 96 * SC;
    if (idx >= 3 * per) return;
    int layer = idx / per, rem = idx - layer * per;
    int j = rem / SC, k = rem - j * SC;
    const float* wl = (layer == 0) ? w1l : (layer == 1) ? w2l : w3l;
    const float* wr = (layer == 0) ? w1r : (layer == 1) ? w2r : w3r;
    float v = 0.f;
    if (j < D) {
        if (k < 96) { if (k < D) v = wl[j * D + k]; }
        else        { int kk = k - 96; if (kk < D) v = wr[j * D + kk]; }
    }
    Wcat[idx] = __float2bfloat16(v);
}

// ---------------- x f32 [N][90] -> cat h-region (cols 96..191) bf16, pads zeroed ----------------
__global__ void k_cvt(const float* __restrict__ x, __hip_bfloat16* __restrict__ cat) {
    int idx = blockIdx.x * 256 + threadIdx.x;  // over N_PAD*96 (h-region elems)
    if (idx >= N_PAD * 96) return;
    int n = idx / 96, k = idx - n * 96;
    float v = (n < N_NODES && k < D) ? x[n * D + k] : 0.f;
    cat[n * SC + 96 + k] = __float2bfloat16(v);
}

// ---------------- mean aggregation: 1 wave per node, 16 lanes/edge, 4 edges/step, x2 unroll ----------------
__global__ void k_agg(unsigned int* __restrict__ cat,
                      const int* __restrict__ off, const int* __restrict__ csr) {
    int wid  = (blockIdx.x * 256 + threadIdx.x) >> 6;
    int lane = threadIdx.x & 63;
    if (wid >= N_NODES) return;
    int beg = off[wid], end = off[wid + 1];
    int eg = lane >> 4, sl = lane & 15;
    int col = 48 + 3 * sl;

    float a0 = 0.f, a1 = 0.f, a2 = 0.f, a3 = 0.f, a4 = 0.f, a5 = 0.f;
    int e = beg + eg;
    for (; e + 4 < end; e += 8) {
        int sA = csr[e], sB = csr[e + 4];
        const unsigned int* pA = &cat[sA * SCD + col];
        const unsigned int* pB = &cat[sB * SCD + col];
        unsigned int u0 = pA[0], u1 = pA[1], u2 = pA[2];
        unsigned int v0 = pB[0], v1 = pB[1], v2 = pB[2];
        a0 += bflo(u0) + bflo(v0); a1 += bfhi(u0) + bfhi(v0);
        a2 += bflo(u1) + bflo(v1); a3 += bfhi(u1) + bfhi(v1);
        a4 += bflo(u2) + bflo(v2); a5 += bfhi(u2) + bfhi(v2);
    }
    if (e < end) {
        const unsigned int* pA = &cat[csr[e] * SCD + col];
        unsigned int u0 = pA[0], u1 = pA[1], u2 = pA[2];
        a0 += bflo(u0); a1 += bfhi(u0);
        a2 += bflo(u1); a3 += bfhi(u1);
        a4 += bflo(u2); a5 += bfhi(u2);
    }

    // fold edge groups: lanes differing in bits 4,5 hold same sl
    #pragma unroll
    for (int m = 16; m <= 32; m <<= 1) {
        a0 += __shfl_xor(a0, m);
        a1 += __shfl_xor(a1, m);
        a2 += __shfl_xor(a2, m);
        a3 += __shfl_xor(a3, m);
        a4 += __shfl_xor(a4, m);
        a5 += __shfl_xor(a5, m);
    }

    if (eg == 0) {
        float inv = 1.0f / fmaxf((float)(end - beg), 1.0f);
        bool pad = (sl == 15);  // elems 90..95
        unsigned int* q = &cat[wid * SCD + 3 * sl];
        q[0] = pad ? 0u : pack2bf(a0 * inv, a1 * inv);
        q[1] = pad ? 0u : pack2bf(a2 * inv, a3 * inv);
        q[2] = pad ? 0u : pack2bf(a4 * inv, a5 * inv);
    }
}

// ---------------- MFMA dual-GEMM + bias + ReLU ----------------
__global__ __launch_bounds__(256) void k_gemm(
    const __hip_bfloat16* __restrict__ Acat,  // [N_PAD][192]
    const __hip_bfloat16* __restrict__ Wcat,  // [96][192]
    const float* __restrict__ bias,           // [90]
    __hip_bfloat16* __restrict__ Hout)        // [N_PAD][192], writes cols 96..191
{
    __shared__ float biasPad[96];
    int tid = threadIdx.x;
    if (tid < 96) biasPad[tid] = (tid < D) ? bias[tid] : 0.f;
    __syncthreads();

    int w = tid >> 6, lane = tid & 63;
    int r0 = blockIdx.x * 64 + w * 16;
    int mrow = lane & 15, kg = lane >> 4;   // A row within tile; k-group 0..3

    const short* A = (const short*)Acat;
    const short* W = (const short*)Wcat;

    f32x4 acc[6];
    #pragma unroll
    for (int t = 0; t < 6; ++t) {
        float b = biasPad[t * 16 + mrow];   // C col = lane&15
        acc[t] = (f32x4){b, b, b, b};
    }

    #pragma unroll
    for (int ks = 0; ks < 6; ++ks) {
        bf16x8 a = *(const bf16x8*)&A[(r0 + mrow) * SC + ks * 32 + kg * 8];
        #pragma unroll
        for (int t = 0; t < 6; ++t) {
            bf16x8 bfr = *(const bf16x8*)&W[(t * 16 + mrow) * SC + ks * 32 + kg * 8];
            acc[t] = __builtin_amdgcn_mfma_f32_16x16x32_bf16(a, bfr, acc[t], 0, 0, 0);
        }
    }

    // C/D layout (m89): col = lane&15, row = (lane>>4)*4 + v
    int orow = r0 + kg * 4;
    #pragma unroll
    for (int t = 0; t < 6; ++t) {
        int j = t * 16 + mrow;
        #pragma unroll
        for (int v = 0; v < 4; ++v) {
            float val = (j < D) ? fmaxf(acc[t][v], 0.f) : 0.f;
            Hout[(orow + v) * SC + 96 + j] = __float2bfloat16(val);
        }
    }
}

// ---------------- graph mean pool: segmented reduction (batch sorted), high-parallelism ----------------
#define POOL_WAVES 4096
__global__ void k_pool(const unsigned int* __restrict__ cat, const int* __restrict__ batch,
                       float* __restrict__ pooled, float* __restrict__ cntg) {
    int wid  = (blockIdx.x * blockDim.x + threadIdx.x) >> 6;
    int lane = threadIdx.x & 63;
    const int per = (N_NODES + POOL_WAVES - 1) / POOL_WAVES;  // 13
    int beg = wid * per;
    int end = beg + per; if (end > N_NODES) end = N_NODES;
    if (beg >= end) return;
    int cur = batch[beg];
    float a0 = 0.f, a1 = 0.f, c = 0.f;
    for (int n = beg; n < end; ++n) {
        int g = batch[n];
        if (g != cur) {
            if (lane < 45) {
                atomicAdd(&pooled[cur * D + 2 * lane], a0);
                atomicAdd(&pooled[cur * D + 2 * lane + 1], a1);
            }
            if (lane == 0) atomicAdd(&cntg[cur], c);
            a0 = a1 = c = 0.f;
            cur = g;
        }
        if (lane < 45) {
            unsigned int v = cat[n * SCD + 48 + lane];
            a0 += bflo(v);
            a1 += bfhi(v);
        }
        c += 1.f;
    }
    if (lane < 45) {
        atomicAdd(&pooled[cur * D + 2 * lane], a0);
        atomicAdd(&pooled[cur * D + 2 * lane + 1], a1);
    }
    if (lane == 0) atomicAdd(&cntg[cur], c);
}

// ---------------- final MLP (single block) ----------------
__global__ void k_mlp(const float* __restrict__ pooled, const float* __restrict__ cntg,
                      const float* __restrict__ Wf1, const float* __restrict__ bf1,
                      const float* __restrict__ Wf2, const float* __restrict__ bf2,
                      float* __restrict__ outp) {
    __shared__ float P[N_GRAPHS][92];
    __shared__ float H4[N_GRAPHS][32];
    int tid = threadIdx.x;
    for (int idx = tid; idx < N_GRAPHS * D; idx += 256) {
        int g = idx / D, d = idx - g * D;
        P[g][d] = pooled[idx] / fmaxf(cntg[g], 1.0f);
    }
    __syncthreads();
    for (int idx = tid; idx < N_GRAPHS * 32; idx += 256) {
        int g = idx >> 5, c = idx & 31;
        float acc = bf1[c];
        for (int d = 0; d < D; ++d) acc += P[g][d] * Wf1[c * D + d];
        H4[g][c] = fmaxf(acc, 0.f);
    }
    __syncthreads();
    if (tid < N_GRAPHS) {
        float acc = bf2[0];
        #pragma unroll
        for (int c = 0; c < 32; ++c) acc += H4[tid][c] * Wf2[c];
        outp[tid] = acc;
    }
}

extern "C" void kernel_launch(void* const* d_in, const int* in_sizes, int n_in,
                              void* d_out, int out_size, void* d_ws, size_t ws_size,
                              hipStream_t stream) {
    const float* x    = (const float*)d_in[0];
    const int*   ei   = (const int*)d_in[1];
    const int*   batch= (const int*)d_in[2];
    const float* W1l  = (const float*)d_in[3];
    const float* b1   = (const float*)d_in[4];
    const float* W1r  = (const float*)d_in[5];
    const float* W2l  = (const float*)d_in[6];
    const float* b2   = (const float*)d_in[7];
    const float* W2r  = (const float*)d_in[8];
    const float* W3l  = (const float*)d_in[9];
    const float* b3   = (const float*)d_in[10];
    const float* W3r  = (const float*)d_in[11];
    const float* Wf1  = (const float*)d_in[12];
    const float* bf1  = (const float*)d_in[13];
    const float* Wf2  = (const float*)d_in[14];
    const float* bf2  = (const float*)d_in[15];
    const int* srcI = ei;
    const int* dstI = ei + N_EDGES;

    char* base = (char*)d_ws;
    size_t o = 0;
    auto alloc = [&](size_t bytes) -> void* {
        void* p = base + o;
        o = (o + bytes + 255) & ~(size_t)255;
        return p;
    };
    int*   bcnt    = (int*)alloc((size_t)NBUCKETS * 4);
    int*   bbase   = (int*)alloc((size_t)(NBUCKETS + 1) * 4);
    int*   bcursor = (int*)alloc((size_t)NBUCKETS * 4);
    int*   off     = (int*)alloc((size_t)(N_NODES + 1) * 4);
    unsigned int* ebuf = (unsigned int*)alloc((size_t)N_EDGES * 4);
    int*   csr     = (int*)alloc((size_t)N_EDGES * 4);
    __hip_bfloat16* catA = (__hip_bfloat16*)alloc((size_t)N_PAD * SC * 2);
    __hip_bfloat16* catB = (__hip_bfloat16*)alloc((size_t)N_PAD * SC * 2);
    __hip_bfloat16* Wcat = (__hip_bfloat16*)alloc((size_t)3 * 96 * SC * 2);
    float* pooled = (float*)alloc((size_t)(N_GRAPHS * D + N_GRAPHS) * 4);
    float* cntg   = pooled + N_GRAPHS * D;

    // zero-init bcnt + pooled in one tiny kernel (hipMemsetAsync's fill kernel
    // cost ~40us each in-graph; this is ~2us)
    const int INIT_N = N_GRAPHS * D + N_GRAPHS;  // 5824 > NBUCKETS
    k_init<<<(INIT_N + 255) / 256, 256, 0, stream>>>(bcnt, pooled);

    const int EB = (N_EDGES + BIN_EPB - 1) / BIN_EPB;  // 196
    k_hist<<<EB, 256, 0, stream>>>(dstI, bcnt);
    k_bscan<<<1, 256, 0, stream>>>(bcnt, bbase, bcursor);
    k_bin<<<EB, 256, 0, stream>>>(srcI, dstI, bcursor, ebuf);
    k_fill2<<<NBUCKETS, 256, 0, stream>>>(ebuf, bbase, off, csr);
    k_prepw<<<(3 * 96 * SC + 255) / 256, 256, 0, stream>>>(W1l, W1r, W2l, W2r, W3l, W3r, Wcat);
    k_cvt<<<(N_PAD * 96 + 255) / 256, 256, 0, stream>>>(x, catA);

    const int AGG_BLOCKS  = N_NODES / 4;   // 12500 (4 waves/block, 1 node/wave)
    const int GEMM_BLOCKS = N_PAD / 64;    // 782

    unsigned int* catAu = (unsigned int*)catA;
    unsigned int* catBu = (unsigned int*)catB;

    // layer 1: agg(x) into catA cols 0..95; gemm catA -> catB h-region
    k_agg<<<AGG_BLOCKS, 256, 0, stream>>>(catAu, off, csr);
    k_gemm<<<GEMM_BLOCKS, 256, 0, stream>>>(catA, Wcat, b1, catB);
    // layer 2
    k_agg<<<AGG_BLOCKS, 256, 0, stream>>>(catBu, off, csr);
    k_gemm<<<GEMM_BLOCKS, 256, 0, stream>>>(catB, Wcat + 96 * SC, b2, catA);
    // layer 3
    k_agg<<<AGG_BLOCKS, 256, 0, stream>>>(catAu, off, csr);
    k_gemm<<<GEMM_BLOCKS, 256, 0, stream>>>(catA, Wcat + 2 * 96 * SC, b3, catB);

    k_pool<<<POOL_WAVES / 4, 256, 0, stream>>>(catBu, batch, pooled, cntg);
    k_mlp<<<1, 256, 0, stream>>>(pooled, cntg, Wf1, bf1, Wf2, bf2, (float*)d_out);
}

// Round 10
// 240.303 us; speedup vs baseline: 5.0145x; 1.0391x over previous
//
#include <hip/hip_runtime.h>
#include <hip/hip_bf16.h>

#define N_NODES 50000
#define N_PAD   50048   // padded to multiple of 64 rows
#define N_EDGES 800000
#define N_GRAPHS 64
#define D 90
#define SC  192   // cat row stride, bf16 elems: [agg(96) | h(96)]
#define SCD 96    // cat row stride in dwords

#define NBUCKETS 196    // ceil(N_NODES/256): 256 nodes per bucket
#define BSHIFT 8
#define BIN_EPB 4096    // edges per block in hist/bin

typedef __attribute__((ext_vector_type(8))) short bf16x8;
typedef __attribute__((ext_vector_type(4))) float f32x4;

__device__ __forceinline__ float bflo(unsigned int v) { return __uint_as_float(v << 16); }
__device__ __forceinline__ float bfhi(unsigned int v) { return __uint_as_float(v & 0xffff0000u); }
__device__ __forceinline__ unsigned short bf16bits(float f) {
    __hip_bfloat16 b = __float2bfloat16(f);
    return *(unsigned short*)&b;
}
__device__ __forceinline__ unsigned int pack2bf(float lo, float hi) {
    return (unsigned int)bf16bits(lo) | ((unsigned int)bf16bits(hi) << 16);
}

// ---------------- fused head: x->bf16 cvt, W pack, zero-init (was 3 kernels) ----------------
__global__ void k_prep(const float* __restrict__ x, __hip_bfloat16* __restrict__ cat,
                       const float* __restrict__ w1l, const float* __restrict__ w1r,
                       const float* __restrict__ w2l, const float* __restrict__ w2r,
                       const float* __restrict__ w3l, const float* __restrict__ w3r,
                       __hip_bfloat16* __restrict__ Wcat,
                       int* __restrict__ bcnt, float* __restrict__ pooled) {
    int idx = blockIdx.x * 256 + threadIdx.x;
    if (idx < N_PAD * 96) {
        int n = idx / 96, k = idx - n * 96;
        float v = (n < N_NODES && k < D) ? x[n * D + k] : 0.f;
        cat[n * SC + 96 + k] = __float2bfloat16(v);
    }
    if (idx < 3 * 96 * SC) {
        const int per = 96 * SC;
        int layer = idx / per, rem = idx - layer * per;
        int j = rem / SC, k = rem - j * SC;
        const float* wl = (layer == 0) ? w1l : (layer == 1) ? w2l : w3l;
        const float* wr = (layer == 0) ? w1r : (layer == 1) ? w2r : w3r;
        float v = 0.f;
        if (j < D) {
            if (k < 96) { if (k < D) v = wl[j * D + k]; }
            else        { int kk = k - 96; if (kk < D) v = wr[j * D + kk]; }
        }
        Wcat[idx] = __float2bfloat16(v);
    }
    if (idx < N_GRAPHS * D + N_GRAPHS) pooled[idx] = 0.f;
    if (idx < NBUCKETS) bcnt[idx] = 0;
}

// ---------------- CSR build: bucket-local, write-coalesced ----------------
__global__ void k_hist(const int* __restrict__ dst, int* __restrict__ bcnt) {
    __shared__ int h[NBUCKETS];
    int t = threadIdx.x;
    for (int i = t; i < NBUCKETS; i += 256) h[i] = 0;
    __syncthreads();
    int base = blockIdx.x * BIN_EPB;
    int lim = base + BIN_EPB; if (lim > N_EDGES) lim = N_EDGES;
    for (int e = base + t; e < lim; e += 256)
        atomicAdd(&h[dst[e] >> BSHIFT], 1);
    __syncthreads();
    for (int i = t; i < NBUCKETS; i += 256) {
        int c = h[i];
        if (c) atomicAdd(&bcnt[i], c);
    }
}

__global__ void k_bscan(const int* __restrict__ bcnt, int* __restrict__ bbase,
                        int* __restrict__ bcursor) {
    __shared__ int s[256];
    int t = threadIdx.x;
    int v = (t < NBUCKETS) ? bcnt[t] : 0;
    s[t] = v; __syncthreads();
    for (int o = 1; o < 256; o <<= 1) {
        int x = (t >= o) ? s[t - o] : 0;
        __syncthreads();
        s[t] += x;
        __syncthreads();
    }
    int excl = s[t] - v;
    if (t < NBUCKETS) { bbase[t] = excl; bcursor[t] = excl; }
    if (t == 255) bbase[NBUCKETS] = s[255];   // total = N_EDGES
}

__global__ __launch_bounds__(256) void k_bin(const int* __restrict__ src,
                                             const int* __restrict__ dst,
                                             int* __restrict__ bcursor,
                                             unsigned int* __restrict__ ebuf) {
    __shared__ int h[NBUCKETS];
    __shared__ int gb[NBUCKETS];
    int t = threadIdx.x;
    for (int i = t; i < NBUCKETS; i += 256) h[i] = 0;
    __syncthreads();
    int base = blockIdx.x * BIN_EPB;
    int sv[16], dv[16], rv[16];
    #pragma unroll
    for (int i = 0; i < 16; ++i) {
        int e = base + i * 256 + t;
        if (e < N_EDGES) {
            sv[i] = src[e];
            dv[i] = dst[e];
            rv[i] = atomicAdd(&h[dv[i] >> BSHIFT], 1);
        }
    }
    __syncthreads();
    for (int i = t; i < NBUCKETS; i += 256)
        gb[i] = h[i] ? atomicAdd(&bcursor[i], h[i]) : 0;
    __syncthreads();
    #pragma unroll
    for (int i = 0; i < 16; ++i) {
        int e = base + i * 256 + t;
        if (e < N_EDGES) {
            int b = dv[i] >> BSHIFT;
            ebuf[gb[b] + rv[i]] = (unsigned int)sv[i] | ((unsigned int)(dv[i] & 255) << 16);
        }
    }
}

__global__ __launch_bounds__(256) void k_fill2(const unsigned int* __restrict__ ebuf,
                                               const int* __restrict__ bbase,
                                               int* __restrict__ off,
                                               int* __restrict__ csr) {
    __shared__ int lcnt[256];
    __shared__ int excl[256];
    int t = threadIdx.x;
    int n0 = blockIdx.x << BSHIFT;
    int ebeg = bbase[blockIdx.x], eend = bbase[blockIdx.x + 1];
    lcnt[t] = 0;
    __syncthreads();
    for (int e = ebeg + t; e < eend; e += 256)
        atomicAdd(&lcnt[ebuf[e] >> 16], 1);
    __syncthreads();
    int v = lcnt[t];
    excl[t] = v; __syncthreads();
    for (int o = 1; o < 256; o <<= 1) {
        int x = (t >= o) ? excl[t - o] : 0;
        __syncthreads();
        excl[t] += x;
        __syncthreads();
    }
    excl[t] -= v;           // exclusive prefix within bucket
    int n = n0 + t;
    if (n <= N_NODES) off[n] = ebeg + excl[t];
    lcnt[t] = 0;
    __syncthreads();
    for (int e = ebeg + t; e < eend; e += 256) {
        unsigned int u = ebuf[e];
        int li = u >> 16;
        int r = atomicAdd(&lcnt[li], 1);
        csr[ebeg + excl[li] + r] = (int)(u & 0xFFFFu);
    }
}

// ---------------- mean aggregation: 1 wave per node, 8 lanes/edge, 8 edges/step, x2 unroll ----------------
// lane = (eg = lane>>3, sl = lane&7): loads dwords [48+6sl, 48+6sl+6) of source row
// (dwordx4+dwordx2); 16 edges in flight per wave. shfl_xor(8|16|32) folds the
// 8 edge-groups; lanes 0..7 of eg 0 write the 48-dword agg region.
__global__ void k_agg(unsigned int* __restrict__ cat,
                      const int* __restrict__ off, const int* __restrict__ csr) {
    int wid  = (blockIdx.x * 256 + threadIdx.x) >> 6;
    int lane = threadIdx.x & 63;
    if (wid >= N_NODES) return;
    int beg = off[wid], end = off[wid + 1];
    int eg = lane >> 3, sl = lane & 7;
    int col = 48 + 6 * sl;

    float a[12];
    #pragma unroll
    for (int i = 0; i < 12; ++i) a[i] = 0.f;

    int e = beg + eg;
    for (; e + 8 < end; e += 16) {
        int sA = csr[e], sB = csr[e + 8];
        const unsigned int* pA = &cat[sA * SCD + col];
        const unsigned int* pB = &cat[sB * SCD + col];
        unsigned int u[6], v[6];
        #pragma unroll
        for (int i = 0; i < 6; ++i) u[i] = pA[i];
        #pragma unroll
        for (int i = 0; i < 6; ++i) v[i] = pB[i];
        #pragma unroll
        for (int i = 0; i < 6; ++i) {
            a[2 * i]     += bflo(u[i]) + bflo(v[i]);
            a[2 * i + 1] += bfhi(u[i]) + bfhi(v[i]);
        }
    }
    if (e < end) {
        const unsigned int* pA = &cat[csr[e] * SCD + col];
        unsigned int u[6];
        #pragma unroll
        for (int i = 0; i < 6; ++i) u[i] = pA[i];
        #pragma unroll
        for (int i = 0; i < 6; ++i) {
            a[2 * i]     += bflo(u[i]);
            a[2 * i + 1] += bfhi(u[i]);
        }
    }

    // fold the 8 edge groups (lane bits 3,4,5)
    #pragma unroll
    for (int m = 8; m <= 32; m <<= 1) {
        #pragma unroll
        for (int i = 0; i < 12; ++i) a[i] += __shfl_xor(a[i], m);
    }

    if (eg == 0) {
        float inv = 1.0f / fmaxf((float)(end - beg), 1.0f);
        unsigned int* q = &cat[wid * SCD + 6 * sl];
        #pragma unroll
        for (int i = 0; i < 6; ++i) {
            int c0 = 12 * sl + 2 * i;
            float lo = (c0     < D) ? a[2 * i]     * inv : 0.f;
            float hi = (c0 + 1 < D) ? a[2 * i + 1] * inv : 0.f;
            q[i] = pack2bf(lo, hi);
        }
    }
}

// ---------------- MFMA dual-GEMM + bias + ReLU ----------------
__global__ __launch_bounds__(256) void k_gemm(
    const __hip_bfloat16* __restrict__ Acat,  // [N_PAD][192]
    const __hip_bfloat16* __restrict__ Wcat,  // [96][192]
    const float* __restrict__ bias,           // [90]
    __hip_bfloat16* __restrict__ Hout)        // [N_PAD][192], writes cols 96..191
{
    __shared__ float biasPad[96];
    int tid = threadIdx.x;
    if (tid < 96) biasPad[tid] = (tid < D) ? bias[tid] : 0.f;
    __syncthreads();

    int w = tid >> 6, lane = tid & 63;
    int r0 = blockIdx.x * 64 + w * 16;
    int mrow = lane & 15, kg = lane >> 4;   // A row within tile; k-group 0..3

    const short* A = (const short*)Acat;
    const short* W = (const short*)Wcat;

    f32x4 acc[6];
    #pragma unroll
    for (int t = 0; t < 6; ++t) {
        float b = biasPad[t * 16 + mrow];   // C col = lane&15
        acc[t] = (f32x4){b, b, b, b};
    }

    #pragma unroll
    for (int ks = 0; ks < 6; ++ks) {
        bf16x8 a = *(const bf16x8*)&A[(r0 + mrow) * SC + ks * 32 + kg * 8];
        #pragma unroll
        for (int t = 0; t < 6; ++t) {
            bf16x8 bfr = *(const bf16x8*)&W[(t * 16 + mrow) * SC + ks * 32 + kg * 8];
            acc[t] = __builtin_amdgcn_mfma_f32_16x16x32_bf16(a, bfr, acc[t], 0, 0, 0);
        }
    }

    // C/D layout (m89): col = lane&15, row = (lane>>4)*4 + v
    int orow = r0 + kg * 4;
    #pragma unroll
    for (int t = 0; t < 6; ++t) {
        int j = t * 16 + mrow;
        #pragma unroll
        for (int v = 0; v < 4; ++v) {
            float val = (j < D) ? fmaxf(acc[t][v], 0.f) : 0.f;
            Hout[(orow + v) * SC + 96 + j] = __float2bfloat16(val);
        }
    }
}

// ---------------- graph mean pool: segmented reduction (batch sorted), high-parallelism ----------------
#define POOL_WAVES 4096
__global__ void k_pool(const unsigned int* __restrict__ cat, const int* __restrict__ batch,
                       float* __restrict__ pooled, float* __restrict__ cntg) {
    int wid  = (blockIdx.x * blockDim.x + threadIdx.x) >> 6;
    int lane = threadIdx.x & 63;
    const int per = (N_NODES + POOL_WAVES - 1) / POOL_WAVES;  // 13
    int beg = wid * per;
    int end = beg + per; if (end > N_NODES) end = N_NODES;
    if (beg >= end) return;
    int cur = batch[beg];
    float a0 = 0.f, a1 = 0.f, c = 0.f;
    for (int n = beg; n < end; ++n) {
        int g = batch[n];
        if (g != cur) {
            if (lane < 45) {
                atomicAdd(&pooled[cur * D + 2 * lane], a0);
                atomicAdd(&pooled[cur * D + 2 * lane + 1], a1);
            }
            if (lane == 0) atomicAdd(&cntg[cur], c);
            a0 = a1 = c = 0.f;
            cur = g;
        }
        if (lane < 45) {
            unsigned int v = cat[n * SCD + 48 + lane];
            a0 += bflo(v);
            a1 += bfhi(v);
        }
        c += 1.f;
    }
    if (lane < 45) {
        atomicAdd(&pooled[cur * D + 2 * lane], a0);
        atomicAdd(&pooled[cur * D + 2 * lane + 1], a1);
    }
    if (lane == 0) atomicAdd(&cntg[cur], c);
}

// ---------------- final MLP (single block) ----------------
__global__ void k_mlp(const float* __restrict__ pooled, const float* __restrict__ cntg,
                      const float* __restrict__ Wf1, const float* __restrict__ bf1,
                      const float* __restrict__ Wf2, const float* __restrict__ bf2,
                      float* __restrict__ outp) {
    __shared__ float P[N_GRAPHS][92];
    __shared__ float H4[N_GRAPHS][32];
    int tid = threadIdx.x;
    for (int idx = tid; idx < N_GRAPHS * D; idx += 256) {
        int g = idx / D, d = idx - g * D;
        P[g][d] = pooled[idx] / fmaxf(cntg[g], 1.0f);
    }
    __syncthreads();
    for (int idx = tid; idx < N_GRAPHS * 32; idx += 256) {
        int g = idx >> 5, c = idx & 31;
        float acc = bf1[c];
        for (int d = 0; d < D; ++d) acc += P[g][d] * Wf1[c * D + d];
        H4[g][c] = fmaxf(acc, 0.f);
    }
    __syncthreads();
    if (tid < N_GRAPHS) {
        float acc = bf2[0];
        #pragma unroll
        for (int c = 0; c < 32; ++c) acc += H4[tid][c] * Wf2[c];
        outp[tid] = acc;
    }
}

extern "C" void kernel_launch(void* const* d_in, const int* in_sizes, int n_in,
                              void* d_out, int out_size, void* d_ws, size_t ws_size,
                              hipStream_t stream) {
    const float* x    = (const float*)d_in[0];
    const int*   ei   = (const int*)d_in[1];
    const int*   batch= (const int*)d_in[2];
    const float* W1l  = (const float*)d_in[3];
    const float* b1   = (const float*)d_in[4];
    const float* W1r  = (const float*)d_in[5];
    const float* W2l  = (const float*)d_in[6];
    const float* b2   = (const float*)d_in[7];
    const float* W2r  = (const float*)d_in[8];
    const float* W3l  = (const float*)d_in[9];
    const float* b3   = (const float*)d_in[10];
    const float* W3r  = (const float*)d_in[11];
    const float* Wf1  = (const float*)d_in[12];
    const float* bf1  = (const float*)d_in[13];
    const float* Wf2  = (const float*)d_in[14];
    const float* bf2  = (const float*)d_in[15];
    const int* srcI = ei;
    const int* dstI = ei + N_EDGES;

    char* base = (char*)d_ws;
    size_t o = 0;
    auto alloc = [&](size_t bytes) -> void* {
        void* p = base + o;
        o = (o + bytes + 255) & ~(size_t)255;
        return p;
    };
    int*   bcnt    = (int*)alloc((size_t)NBUCKETS * 4);
    int*   bbase   = (int*)alloc((size_t)(NBUCKETS + 1) * 4);
    int*   bcursor = (int*)alloc((size_t)NBUCKETS * 4);
    int*   off     = (int*)alloc((size_t)(N_NODES + 1) * 4);
    unsigned int* ebuf = (unsigned int*)alloc((size_t)N_EDGES * 4);
    int*   csr     = (int*)alloc((size_t)N_EDGES * 4);
    __hip_bfloat16* catA = (__hip_bfloat16*)alloc((size_t)N_PAD * SC * 2);
    __hip_bfloat16* catB = (__hip_bfloat16*)alloc((size_t)N_PAD * SC * 2);
    __hip_bfloat16* Wcat = (__hip_bfloat16*)alloc((size_t)3 * 96 * SC * 2);
    float* pooled = (float*)alloc((size_t)(N_GRAPHS * D + N_GRAPHS) * 4);
    float* cntg   = pooled + N_GRAPHS * D;

    // fused head: cvt + W pack + zero-init (covers the largest range, N_PAD*96)
    k_prep<<<(N_PAD * 96 + 255) / 256, 256, 0, stream>>>(
        x, catA, W1l, W1r, W2l, W2r, W3l, W3r, Wcat, bcnt, pooled);

    const int EB = (N_EDGES + BIN_EPB - 1) / BIN_EPB;  // 196
    k_hist<<<EB, 256, 0, stream>>>(dstI, bcnt);
    k_bscan<<<1, 256, 0, stream>>>(bcnt, bbase, bcursor);
    k_bin<<<EB, 256, 0, stream>>>(srcI, dstI, bcursor, ebuf);
    k_fill2<<<NBUCKETS, 256, 0, stream>>>(ebuf, bbase, off, csr);

    const int AGG_BLOCKS  = N_NODES / 4;   // 12500 (4 waves/block, 1 node/wave)
    const int GEMM_BLOCKS = N_PAD / 64;    // 782

    unsigned int* catAu = (unsigned int*)catA;
    unsigned int* catBu = (unsigned int*)catB;

    // layer 1: agg(x) into catA cols 0..95; gemm catA -> catB h-region
    k_agg<<<AGG_BLOCKS, 256, 0, stream>>>(catAu, off, csr);
    k_gemm<<<GEMM_BLOCKS, 256, 0, stream>>>(catA, Wcat, b1, catB);
    // layer 2
    k_agg<<<AGG_BLOCKS, 256, 0, stream>>>(catBu, off, csr);
    k_gemm<<<GEMM_BLOCKS, 256, 0, stream>>>(catB, Wcat + 96 * SC, b2, catA);
    // layer 3
    k_agg<<<AGG_BLOCKS, 256, 0, stream>>>(catAu, off, csr);
    k_gemm<<<GEMM_BLOCKS, 256, 0, stream>>>(catA, Wcat + 2 * 96 * SC, b3, catB);

    k_pool<<<POOL_WAVES / 4, 256, 0, stream>>>(catBu, batch, pooled, cntg);
    k_mlp<<<1, 256, 0, stream>>>(pooled, cntg, Wf1, bf1, Wf2, bf2, (float*)d_out);
}